// Round 1
// baseline (858.722 us; speedup 1.0000x reference)
//
#include <hip/hip_runtime.h>
#include <hip/hip_bf16.h>

// ---------------- CSR build ----------------

__global__ void count_kernel(const int* __restrict__ dst, int* __restrict__ cnt, int e) {
    int i = blockIdx.x * blockDim.x + threadIdx.x;
    if (i < e) atomicAdd(&cnt[dst[i]], 1);
}

__global__ void dinv_kernel(const int* __restrict__ cnt, float* __restrict__ dinv, int n) {
    int i = blockIdx.x * blockDim.x + threadIdx.x;
    if (i < n) dinv[i] = rsqrtf((float)cnt[i] + 1.0f);
}

// single-block scan: 1024 threads, each owns a contiguous chunk
__global__ __launch_bounds__(1024) void scan_kernel(const int* __restrict__ cnt,
                                                    int* __restrict__ offsets,
                                                    int* __restrict__ cursor, int n) {
    int tid = threadIdx.x;
    int chunk = (n + 1023) >> 10;
    int beg = tid * chunk; if (beg > n) beg = n;
    int end = beg + chunk; if (end > n) end = n;
    int s = 0;
    for (int i = beg; i < end; ++i) s += cnt[i];
    // block exclusive scan of per-thread sums
    int lane = tid & 63, wid = tid >> 6;   // 16 waves
    int v = s;
    #pragma unroll
    for (int off = 1; off < 64; off <<= 1) {
        int t = __shfl_up(v, off);
        if (lane >= off) v += t;
    }
    __shared__ int wsum[16];
    if (lane == 63) wsum[wid] = v;
    __syncthreads();
    if (wid == 0) {
        int w = (lane < 16) ? wsum[lane] : 0;
        #pragma unroll
        for (int off = 1; off < 16; off <<= 1) {
            int t = __shfl_up(w, off);
            if (lane >= off) w += t;
        }
        if (lane < 16) wsum[lane] = w;   // inclusive wave sums
    }
    __syncthreads();
    int waveoff = (wid > 0) ? wsum[wid - 1] : 0;
    int run = waveoff + v - s;           // exclusive prefix for this thread's chunk
    for (int i = beg; i < end; ++i) {
        offsets[i] = run; cursor[i] = run;
        run += cnt[i];
    }
    if (tid == 1023) offsets[n] = run;   // total = E
}

__global__ void fill_kernel(const int* __restrict__ src, const int* __restrict__ dst,
                            int* __restrict__ cursor, int* __restrict__ csr, int e) {
    int i = blockIdx.x * blockDim.x + threadIdx.x;
    if (i < e) {
        int p = atomicAdd(&cursor[dst[i]], 1);
        csr[p] = src[i];
    }
}

// ---------------- SGEMM: C[M,256] = A[M,K] @ W[K,256], fused epilogue ----------------
// MODE 0: C += bias[col]        (input projection)
// MODE 1: C *= dinv[row]        (produce hs = (h@W)*dinv for aggregation)

template <int MODE>
__global__ __launch_bounds__(256) void sgemm_k(const float* __restrict__ A,
                                               const float* __restrict__ W,
                                               const float* __restrict__ aux,
                                               float* __restrict__ C, int M, int K) {
    const int NCOL = 256;
    __shared__ float As[16][136];   // [BK][BM+pad]; 136*4=544B row stride (16B aligned, 2-way max)
    __shared__ float Bs[16][64];
    int tid = threadIdx.x;
    int tx = tid & 15;              // col group (4 cols)
    int ty = tid >> 4;              // row group (8 rows)
    int row0 = blockIdx.x * 128;
    int col0 = blockIdx.y * 64;

    int arow = tid >> 1;            // 0..127
    int acol = (tid & 1) * 8;       // 0 or 8
    int brow = tid >> 4;            // 0..15
    int bcol = (tid & 15) * 4;      // 0..60

    float acc[8][4];
    #pragma unroll
    for (int i = 0; i < 8; ++i)
        #pragma unroll
        for (int j = 0; j < 4; ++j) acc[i][j] = 0.f;

    bool aValid = (row0 + arow) < M;
    const float* Aptr = A + (size_t)(row0 + arow) * K + acol;

    for (int k0 = 0; k0 < K; k0 += 16) {
        float4 av0 = make_float4(0.f, 0.f, 0.f, 0.f);
        float4 av1 = make_float4(0.f, 0.f, 0.f, 0.f);
        if (aValid) {
            av0 = *(const float4*)(Aptr + k0);
            av1 = *(const float4*)(Aptr + k0 + 4);
        }
        float4 bv = *(const float4*)&W[(size_t)(k0 + brow) * NCOL + col0 + bcol];
        As[acol + 0][arow] = av0.x; As[acol + 1][arow] = av0.y;
        As[acol + 2][arow] = av0.z; As[acol + 3][arow] = av0.w;
        As[acol + 4][arow] = av1.x; As[acol + 5][arow] = av1.y;
        As[acol + 6][arow] = av1.z; As[acol + 7][arow] = av1.w;
        *(float4*)&Bs[brow][bcol] = bv;
        __syncthreads();
        #pragma unroll
        for (int kk = 0; kk < 16; ++kk) {
            float4 a0 = *(const float4*)&As[kk][ty * 8];
            float4 a1 = *(const float4*)&As[kk][ty * 8 + 4];
            float4 b  = *(const float4*)&Bs[kk][tx * 4];
            float am[8] = {a0.x, a0.y, a0.z, a0.w, a1.x, a1.y, a1.z, a1.w};
            float bm[4] = {b.x, b.y, b.z, b.w};
            #pragma unroll
            for (int i = 0; i < 8; ++i)
                #pragma unroll
                for (int j = 0; j < 4; ++j) acc[i][j] = fmaf(am[i], bm[j], acc[i][j]);
        }
        __syncthreads();
    }

    float4 bias4;
    if (MODE == 0) bias4 = *(const float4*)&aux[col0 + tx * 4];
    #pragma unroll
    for (int i = 0; i < 8; ++i) {
        int r = row0 + ty * 8 + i;
        if (r < M) {
            float4 v = make_float4(acc[i][0], acc[i][1], acc[i][2], acc[i][3]);
            if (MODE == 0) {
                v.x += bias4.x; v.y += bias4.y; v.z += bias4.z; v.w += bias4.w;
            } else {
                float d = aux[r];
                v.x *= d; v.y *= d; v.z *= d; v.w *= d;
            }
            *(float4*)&C[(size_t)r * NCOL + col0 + tx * 4] = v;
        }
    }
}

// ---------------- aggregation: out[n] = relu(dinv[n]*(sum_{e->n} hs[src] + hs[n]) + b) ----------------
// one wave per node, lane handles 4 channels (float4)

__global__ __launch_bounds__(256) void agg_kernel(const float* __restrict__ hs,
                                                  const int* __restrict__ offsets,
                                                  const int* __restrict__ csr,
                                                  const float* __restrict__ dinv,
                                                  const float* __restrict__ bias,
                                                  float* __restrict__ out, int n) {
    int node = blockIdx.x * 4 + (threadIdx.x >> 6);
    if (node >= n) return;
    int lane = threadIdx.x & 63;
    const float4* hs4 = (const float4*)hs;
    int beg = offsets[node], end = offsets[node + 1];
    float4 acc = hs4[(size_t)node * 64 + lane];   // self-loop term (hs[n])
    for (int e = beg; e < end; ++e) {
        int s = csr[e];
        float4 v = hs4[(size_t)s * 64 + lane];
        acc.x += v.x; acc.y += v.y; acc.z += v.z; acc.w += v.w;
    }
    float d = dinv[node];
    float4 b = ((const float4*)bias)[lane];
    float4 r;
    r.x = fmaxf(fmaf(acc.x, d, b.x), 0.f);
    r.y = fmaxf(fmaf(acc.y, d, b.y), 0.f);
    r.z = fmaxf(fmaf(acc.z, d, b.z), 0.f);
    r.w = fmaxf(fmaf(acc.w, d, b.w), 0.f);
    ((float4*)out)[(size_t)node * 64 + lane] = r;
}

// ---------------- pool + output head ----------------
// block per graph: mean over [beg,end) into LDS, then 16-col GEMV

__device__ __forceinline__ int lower_bound(const int* a, int n, int key) {
    int lo = 0, hi = n;
    while (lo < hi) {
        int mid = (lo + hi) >> 1;
        if (a[mid] < key) lo = mid + 1; else hi = mid;
    }
    return lo;
}

__global__ __launch_bounds__(256) void pool_out_kernel(const float* __restrict__ h,
                                                       const int* __restrict__ batch,
                                                       const float* __restrict__ Wout,
                                                       const float* __restrict__ bout,
                                                       float* __restrict__ out, int n) {
    __shared__ float pl[256];
    int g = blockIdx.x;
    int c = threadIdx.x;
    int beg = lower_bound(batch, n, g);
    int end = lower_bound(batch, n, g + 1);
    float s = 0.f;
    for (int i = beg; i < end; ++i) s += h[(size_t)i * 256 + c];
    int cntv = end - beg;
    pl[c] = s / (float)(cntv > 0 ? cntv : 1);
    __syncthreads();
    if (c < 16) {
        float o = bout[c];
        for (int k = 0; k < 256; ++k) o = fmaf(pl[k], Wout[k * 16 + c], o);
        out[g * 16 + c] = o;
    }
}

// ---------------- launch ----------------

extern "C" void kernel_launch(void* const* d_in, const int* in_sizes, int n_in,
                              void* d_out, int out_size, void* d_ws, size_t ws_size,
                              hipStream_t stream) {
    const float* x     = (const float*)d_in[0];
    const int*   ei    = (const int*)d_in[1];
    const int*   batch = (const int*)d_in[2];
    const float* W_in  = (const float*)d_in[3];
    const float* b_in  = (const float*)d_in[4];
    const float* W1    = (const float*)d_in[5];
    const float* b1    = (const float*)d_in[6];
    const float* W2    = (const float*)d_in[7];
    const float* b2    = (const float*)d_in[8];
    const float* Wout  = (const float*)d_in[9];
    const float* bout  = (const float*)d_in[10];

    const int E = in_sizes[1] / 2;
    const int N = in_sizes[2];
    const int IN_DIM = in_sizes[0] / N;   // 128
    const int* src = ei;
    const int* dst = ei + E;

    char* ws = (char*)d_ws;
    size_t off = 0;
    auto alloc = [&](size_t bytes) { size_t p = off; off += (bytes + 255) & ~(size_t)255; return p; };
    float* buf0    = (float*)(ws + alloc((size_t)N * 256 * 4));
    float* buf1    = (float*)(ws + alloc((size_t)N * 256 * 4));
    int*   deg_cnt = (int*)(ws + alloc((size_t)N * 4));
    float* dinv    = (float*)(ws + alloc((size_t)N * 4));
    int*   offsets = (int*)(ws + alloc((size_t)(N + 1) * 4));
    int*   cursor  = (int*)(ws + alloc((size_t)N * 4));
    int*   csr     = (int*)(ws + alloc((size_t)E * 4));
    (void)ws_size;

    // graph structure (per call — inputs re-poisoned every launch)
    hipMemsetAsync(deg_cnt, 0, (size_t)N * 4, stream);
    count_kernel<<<(E + 255) / 256, 256, 0, stream>>>(dst, deg_cnt, E);
    dinv_kernel<<<(N + 255) / 256, 256, 0, stream>>>(deg_cnt, dinv, N);
    scan_kernel<<<1, 1024, 0, stream>>>(deg_cnt, offsets, cursor, N);
    fill_kernel<<<(E + 255) / 256, 256, 0, stream>>>(src, dst, cursor, csr, E);

    dim3 gg((N + 127) / 128, 256 / 64);
    // h0 = x @ W_in + b_in
    sgemm_k<0><<<gg, 256, 0, stream>>>(x, W_in, b_in, buf0, N, IN_DIM);
    // layer 1: hs = (h0 @ W1) * dinv ; h = relu(dinv*(gather-sum + hs) + b1)
    sgemm_k<1><<<gg, 256, 0, stream>>>(buf0, W1, dinv, buf1, N, 256);
    agg_kernel<<<(N + 3) / 4, 256, 0, stream>>>(buf1, offsets, csr, dinv, b1, buf0, N);
    // layer 2
    sgemm_k<1><<<gg, 256, 0, stream>>>(buf0, W2, dinv, buf1, N, 256);
    agg_kernel<<<(N + 3) / 4, 256, 0, stream>>>(buf1, offsets, csr, dinv, b2, buf0, N);
    // pool + head
    pool_out_kernel<<<128, 256, 0, stream>>>(buf0, batch, Wout, bout, (float*)d_out, N);
}

// Round 2
// 591.321 us; speedup vs baseline: 1.4522x; 1.4522x over previous
//
#include <hip/hip_runtime.h>
#include <hip/hip_bf16.h>

typedef __attribute__((ext_vector_type(8))) short bf16x8;   // 8 bf16 in 4 VGPRs (MFMA A/B frag)
typedef __attribute__((ext_vector_type(4))) float f32x4;    // MFMA C/D frag

__device__ __forceinline__ unsigned short f2bf(float f) {   // RNE fp32->bf16
    unsigned u = __float_as_uint(f);
    u += 0x7fff + ((u >> 16) & 1);
    return (unsigned short)(u >> 16);
}
__device__ __forceinline__ float bf2f(unsigned short s) {
    return __uint_as_float(((unsigned)s) << 16);
}

#define GL2LDS16(g, l) __builtin_amdgcn_global_load_lds(                      \
        (const __attribute__((address_space(1))) void*)(g),                   \
        (__attribute__((address_space(3))) void*)(l), 16, 0, 0)

// ---------------- CSR build ----------------

__global__ void count_kernel(const int* __restrict__ dst, int* __restrict__ cnt, int e) {
    int i = blockIdx.x * blockDim.x + threadIdx.x;
    if (i < e) atomicAdd(&cnt[dst[i]], 1);
}

__global__ void dinv_kernel(const int* __restrict__ cnt, float* __restrict__ dinv, int n) {
    int i = blockIdx.x * blockDim.x + threadIdx.x;
    if (i < n) dinv[i] = rsqrtf((float)cnt[i] + 1.0f);
}

__global__ __launch_bounds__(1024) void scan_kernel(const int* __restrict__ cnt,
                                                    int* __restrict__ offsets,
                                                    int* __restrict__ cursor, int n) {
    int tid = threadIdx.x;
    int chunk = (n + 1023) >> 10;
    int beg = tid * chunk; if (beg > n) beg = n;
    int end = beg + chunk; if (end > n) end = n;
    int s = 0;
    for (int i = beg; i < end; ++i) s += cnt[i];
    int lane = tid & 63, wid = tid >> 6;   // 16 waves
    int v = s;
    #pragma unroll
    for (int off = 1; off < 64; off <<= 1) {
        int t = __shfl_up(v, off);
        if (lane >= off) v += t;
    }
    __shared__ int wsum[16];
    if (lane == 63) wsum[wid] = v;
    __syncthreads();
    if (wid == 0) {
        int w = (lane < 16) ? wsum[lane] : 0;
        #pragma unroll
        for (int off = 1; off < 16; off <<= 1) {
            int t = __shfl_up(w, off);
            if (lane >= off) w += t;
        }
        if (lane < 16) wsum[lane] = w;
    }
    __syncthreads();
    int waveoff = (wid > 0) ? wsum[wid - 1] : 0;
    int run = waveoff + v - s;
    for (int i = beg; i < end; ++i) {
        offsets[i] = run; cursor[i] = run;
        run += cnt[i];
    }
    if (tid == 1023) offsets[n] = run;
}

__global__ void fill_kernel(const int* __restrict__ src, const int* __restrict__ dst,
                            int* __restrict__ cursor, int* __restrict__ csr, int e) {
    int i = blockIdx.x * blockDim.x + threadIdx.x;
    if (i < e) {
        int p = atomicAdd(&cursor[dst[i]], 1);
        csr[p] = src[i];
    }
}

// ---------------- conversions ----------------

// W[K][256] fp32 -> Wt[256][K] bf16 (transposed for MFMA B-operand layout)
__global__ void convt_kernel(const float* __restrict__ W, unsigned short* __restrict__ Wt,
                             int K, int NCOL) {
    int i = blockIdx.x * blockDim.x + threadIdx.x;
    if (i < K * NCOL) {
        int k = i / NCOL, n = i - k * NCOL;
        Wt[(size_t)n * K + k] = f2bf(W[i]);
    }
}

// x fp32 -> bf16, vectorized float4 -> ushort4
__global__ void convx_kernel(const float* __restrict__ x, unsigned short* __restrict__ xb, int n4) {
    int i = blockIdx.x * blockDim.x + threadIdx.x;
    if (i < n4) {
        float4 v = ((const float4*)x)[i];
        ushort4 o;
        o.x = f2bf(v.x); o.y = f2bf(v.y); o.z = f2bf(v.z); o.w = f2bf(v.w);
        ((ushort4*)xb)[i] = o;
    }
}

// ---------------- bf16 MFMA GEMM: C[M,256] = A[M,K] @ W[K,256] ----------------
// A bf16 row-major, Wt bf16 [256][K] (W transposed), C bf16 row-major.
// MODE 0: +bias[col]   MODE 1: *dinv[row]
// 128x128 block tile, BK=32, 4 waves (2x2), each wave 4x4 MFMAs of 16x16x32.

template <int MODE>
__global__ __launch_bounds__(256) void gemm_bf16(const unsigned short* __restrict__ A,
                                                 const unsigned short* __restrict__ Wt,
                                                 const float* __restrict__ aux,
                                                 unsigned short* __restrict__ C,
                                                 int M, int K) {
    __shared__ unsigned short As[128 * 32];   // [row][k] 8 KB
    __shared__ unsigned short Bs[128 * 32];   // [col][k] 8 KB
    const int tid  = threadIdx.x;
    const int lane = tid & 63;
    const int w    = tid >> 6;
    const int wr   = w >> 1, wc = w & 1;
    const int row0 = blockIdx.x * 128;
    const int col0 = blockIdx.y * 128;
    const int mlane = lane & 15, quad = lane >> 4;

    f32x4 acc[4][4];
    #pragma unroll
    for (int i = 0; i < 4; ++i)
        #pragma unroll
        for (int j = 0; j < 4; ++j) acc[i][j] = f32x4{0.f, 0.f, 0.f, 0.f};

    // staging: 512 chunks of 16B per tile; wave w round p owns chunks [(p*4+w)*64, +64)
    int cid0 = (0 * 4 + w) * 64 + lane;
    int cid1 = (1 * 4 + w) * 64 + lane;
    int r0 = cid0 >> 2, c0 = cid0 & 3;
    int r1 = cid1 >> 2, c1 = cid1 & 3;
    int rowA0 = row0 + r0; if (rowA0 >= M) rowA0 = M - 1;   // clamp tail (dup reads, masked store)
    int rowA1 = row0 + r1; if (rowA1 >= M) rowA1 = M - 1;
    const unsigned short* gA0 = A + (size_t)rowA0 * K + c0 * 8;
    const unsigned short* gA1 = A + (size_t)rowA1 * K + c1 * 8;
    const unsigned short* gB0 = Wt + (size_t)(col0 + r0) * K + c0 * 8;
    const unsigned short* gB1 = Wt + (size_t)(col0 + r1) * K + c1 * 8;
    unsigned short* lA0 = &As[(0 * 4 + w) * 512];   // wave-uniform base; HW adds lane*16B
    unsigned short* lA1 = &As[(1 * 4 + w) * 512];
    unsigned short* lB0 = &Bs[(0 * 4 + w) * 512];
    unsigned short* lB1 = &Bs[(1 * 4 + w) * 512];

    const int aoff = (lane >> 4) * 8;   // k-octet within BK=32

    for (int k0 = 0; k0 < K; k0 += 32) {
        GL2LDS16(gA0 + k0, lA0);
        GL2LDS16(gA1 + k0, lA1);
        GL2LDS16(gB0 + k0, lB0);
        GL2LDS16(gB1 + k0, lB1);
        __syncthreads();
        bf16x8 af[4], bfv[4];
        #pragma unroll
        for (int i = 0; i < 4; ++i)
            af[i] = *(const bf16x8*)&As[(wr * 64 + i * 16 + mlane) * 32 + aoff];
        #pragma unroll
        for (int j = 0; j < 4; ++j)
            bfv[j] = *(const bf16x8*)&Bs[(wc * 64 + j * 16 + mlane) * 32 + aoff];
        #pragma unroll
        for (int i = 0; i < 4; ++i)
            #pragma unroll
            for (int j = 0; j < 4; ++j)
                acc[i][j] = __builtin_amdgcn_mfma_f32_16x16x32_bf16(af[i], bfv[j], acc[i][j], 0, 0, 0);
        __syncthreads();
    }

    // epilogue: D row = quad*4+reg, col = mlane
    float bj[4];
    if (MODE == 0) {
        #pragma unroll
        for (int j = 0; j < 4; ++j) bj[j] = aux[col0 + wc * 64 + j * 16 + mlane];
    }
    #pragma unroll
    for (int i = 0; i < 4; ++i) {
        #pragma unroll
        for (int r = 0; r < 4; ++r) {
            int grow = row0 + wr * 64 + i * 16 + quad * 4 + r;
            if (grow < M) {
                float d = (MODE == 1) ? aux[grow] : 0.f;
                #pragma unroll
                for (int j = 0; j < 4; ++j) {
                    int gcol = col0 + wc * 64 + j * 16 + mlane;
                    float v = acc[i][j][r];
                    v = (MODE == 0) ? (v + bj[j]) : (v * d);
                    C[(size_t)grow * 256 + gcol] = f2bf(v);
                }
            }
        }
    }
}

// ---------------- aggregation (bf16 gather, fp32 accumulate) ----------------
// out[n] = relu(dinv[n]*(sum_{e->n} hs[src] + hs[n]) + b), hs/out bf16

__global__ __launch_bounds__(256) void agg_kernel(const unsigned short* __restrict__ hs,
                                                  const int* __restrict__ offsets,
                                                  const int* __restrict__ csr,
                                                  const float* __restrict__ dinv,
                                                  const float* __restrict__ bias,
                                                  unsigned short* __restrict__ out, int n) {
    int node = blockIdx.x * 4 + (threadIdx.x >> 6);
    if (node >= n) return;
    int lane = threadIdx.x & 63;
    const ushort4* hs4 = (const ushort4*)hs;   // 4 channels per lane, 64 lanes = 256 ch
    int beg = offsets[node], end = offsets[node + 1];
    ushort4 sv = hs4[(size_t)node * 64 + lane];
    float a0 = bf2f(sv.x), a1 = bf2f(sv.y), a2 = bf2f(sv.z), a3 = bf2f(sv.w);
    int e = beg;
    for (; e + 2 <= end; e += 2) {
        int s0 = csr[e], s1 = csr[e + 1];
        ushort4 v0 = hs4[(size_t)s0 * 64 + lane];
        ushort4 v1 = hs4[(size_t)s1 * 64 + lane];
        a0 += bf2f(v0.x) + bf2f(v1.x);
        a1 += bf2f(v0.y) + bf2f(v1.y);
        a2 += bf2f(v0.z) + bf2f(v1.z);
        a3 += bf2f(v0.w) + bf2f(v1.w);
    }
    if (e < end) {
        ushort4 v0 = hs4[(size_t)csr[e] * 64 + lane];
        a0 += bf2f(v0.x); a1 += bf2f(v0.y); a2 += bf2f(v0.z); a3 += bf2f(v0.w);
    }
    float d = dinv[node];
    float4 b = ((const float4*)bias)[lane];
    ushort4 r;
    r.x = f2bf(fmaxf(fmaf(a0, d, b.x), 0.f));
    r.y = f2bf(fmaxf(fmaf(a1, d, b.y), 0.f));
    r.z = f2bf(fmaxf(fmaf(a2, d, b.z), 0.f));
    r.w = f2bf(fmaxf(fmaf(a3, d, b.w), 0.f));
    ((ushort4*)out)[(size_t)node * 64 + lane] = r;
}

// ---------------- pool + output head (fp32 accumulate, fp32 out) ----------------

__device__ __forceinline__ int lower_bound(const int* a, int n, int key) {
    int lo = 0, hi = n;
    while (lo < hi) {
        int mid = (lo + hi) >> 1;
        if (a[mid] < key) lo = mid + 1; else hi = mid;
    }
    return lo;
}

__global__ __launch_bounds__(256) void pool_out_kernel(const unsigned short* __restrict__ h,
                                                       const int* __restrict__ batch,
                                                       const float* __restrict__ Wout,
                                                       const float* __restrict__ bout,
                                                       float* __restrict__ out, int n) {
    __shared__ float pl[256];
    int g = blockIdx.x;
    int c = threadIdx.x;
    int beg = lower_bound(batch, n, g);
    int end = lower_bound(batch, n, g + 1);
    float s = 0.f;
    for (int i = beg; i < end; ++i) s += bf2f(h[(size_t)i * 256 + c]);
    int cntv = end - beg;
    pl[c] = s / (float)(cntv > 0 ? cntv : 1);
    __syncthreads();
    if (c < 16) {
        float o = bout[c];
        for (int k = 0; k < 256; ++k) o = fmaf(pl[k], Wout[k * 16 + c], o);
        out[g * 16 + c] = o;
    }
}

// ---------------- launch ----------------

extern "C" void kernel_launch(void* const* d_in, const int* in_sizes, int n_in,
                              void* d_out, int out_size, void* d_ws, size_t ws_size,
                              hipStream_t stream) {
    const float* x     = (const float*)d_in[0];
    const int*   ei    = (const int*)d_in[1];
    const int*   batch = (const int*)d_in[2];
    const float* W_in  = (const float*)d_in[3];
    const float* b_in  = (const float*)d_in[4];
    const float* W1    = (const float*)d_in[5];
    const float* b1    = (const float*)d_in[6];
    const float* W2    = (const float*)d_in[7];
    const float* b2    = (const float*)d_in[8];
    const float* Wout  = (const float*)d_in[9];
    const float* bout  = (const float*)d_in[10];

    const int E = in_sizes[1] / 2;
    const int N = in_sizes[2];
    const int IN_DIM = in_sizes[0] / N;   // 128
    const int* src = ei;
    const int* dst = ei + E;

    char* ws = (char*)d_ws;
    size_t off = 0;
    auto alloc = [&](size_t bytes) { size_t p = off; off += (bytes + 255) & ~(size_t)255; return p; };
    unsigned short* bufA = (unsigned short*)(ws + alloc((size_t)N * 256 * 2));
    unsigned short* bufB = (unsigned short*)(ws + alloc((size_t)N * 256 * 2));
    unsigned short* xb   = (unsigned short*)(ws + alloc((size_t)N * IN_DIM * 2));
    unsigned short* WtIn = (unsigned short*)(ws + alloc((size_t)IN_DIM * 256 * 2));
    unsigned short* Wt1  = (unsigned short*)(ws + alloc((size_t)256 * 256 * 2));
    unsigned short* Wt2  = (unsigned short*)(ws + alloc((size_t)256 * 256 * 2));
    int*   deg_cnt = (int*)(ws + alloc((size_t)N * 4));
    float* dinv    = (float*)(ws + alloc((size_t)N * 4));
    int*   offsets = (int*)(ws + alloc((size_t)(N + 1) * 4));
    int*   cursor  = (int*)(ws + alloc((size_t)N * 4));
    int*   csr     = (int*)(ws + alloc((size_t)E * 4));
    (void)ws_size;

    // graph structure
    hipMemsetAsync(deg_cnt, 0, (size_t)N * 4, stream);
    count_kernel<<<(E + 255) / 256, 256, 0, stream>>>(dst, deg_cnt, E);
    dinv_kernel<<<(N + 255) / 256, 256, 0, stream>>>(deg_cnt, dinv, N);
    scan_kernel<<<1, 1024, 0, stream>>>(deg_cnt, offsets, cursor, N);
    fill_kernel<<<(E + 255) / 256, 256, 0, stream>>>(src, dst, cursor, csr, E);

    // bf16 conversions
    convt_kernel<<<(IN_DIM * 256 + 255) / 256, 256, 0, stream>>>(W_in, WtIn, IN_DIM, 256);
    convt_kernel<<<(256 * 256 + 255) / 256, 256, 0, stream>>>(W1, Wt1, 256, 256);
    convt_kernel<<<(256 * 256 + 255) / 256, 256, 0, stream>>>(W2, Wt2, 256, 256);
    convx_kernel<<<((N * IN_DIM / 4) + 255) / 256, 256, 0, stream>>>(x, xb, N * IN_DIM / 4);

    dim3 gg((N + 127) / 128, 2);
    // h0 = x @ W_in + b_in
    gemm_bf16<0><<<gg, 256, 0, stream>>>(xb, WtIn, b_in, bufA, N, IN_DIM);
    // layer 1
    gemm_bf16<1><<<gg, 256, 0, stream>>>(bufA, Wt1, dinv, bufB, N, 256);
    agg_kernel<<<(N + 3) / 4, 256, 0, stream>>>(bufB, offsets, csr, dinv, b1, bufA, N);
    // layer 2
    gemm_bf16<1><<<gg, 256, 0, stream>>>(bufA, Wt2, dinv, bufB, N, 256);
    agg_kernel<<<(N + 3) / 4, 256, 0, stream>>>(bufB, offsets, csr, dinv, b2, bufA, N);
    // pool + head
    pool_out_kernel<<<128, 256, 0, stream>>>(bufA, batch, Wout, bout, (float*)d_out, N);
}

// Round 3
// 539.455 us; speedup vs baseline: 1.5918x; 1.0961x over previous
//
#include <hip/hip_runtime.h>
#include <hip/hip_bf16.h>

typedef __attribute__((ext_vector_type(8))) short bf16x8;   // 8 bf16 in 4 VGPRs (MFMA A/B frag)
typedef __attribute__((ext_vector_type(4))) float f32x4;    // MFMA C/D frag

__device__ __forceinline__ unsigned short f2bf(float f) {   // RNE fp32->bf16
    unsigned u = __float_as_uint(f);
    u += 0x7fff + ((u >> 16) & 1);
    return (unsigned short)(u >> 16);
}
__device__ __forceinline__ float bf2f(unsigned short s) {
    return __uint_as_float(((unsigned)s) << 16);
}

#define GL2LDS16(g, l) __builtin_amdgcn_global_load_lds(                      \
        (const __attribute__((address_space(1))) void*)(g),                   \
        (__attribute__((address_space(3))) void*)(l), 16, 0, 0)

// ---------------- CSR build ----------------

__global__ void count_kernel(const int* __restrict__ dst, int* __restrict__ cnt, int e) {
    int i = blockIdx.x * blockDim.x + threadIdx.x;
    if (i < e) atomicAdd(&cnt[dst[i]], 1);
}

__global__ void dinv_kernel(const int* __restrict__ cnt, float* __restrict__ dinv, int n) {
    int i = blockIdx.x * blockDim.x + threadIdx.x;
    if (i < n) dinv[i] = rsqrtf((float)cnt[i] + 1.0f);
}

__global__ __launch_bounds__(1024) void scan_kernel(const int* __restrict__ cnt,
                                                    int* __restrict__ offsets,
                                                    int* __restrict__ cursor, int n) {
    int tid = threadIdx.x;
    int chunk = (n + 1023) >> 10;
    int beg = tid * chunk; if (beg > n) beg = n;
    int end = beg + chunk; if (end > n) end = n;
    int s = 0;
    for (int i = beg; i < end; ++i) s += cnt[i];
    int lane = tid & 63, wid = tid >> 6;   // 16 waves
    int v = s;
    #pragma unroll
    for (int off = 1; off < 64; off <<= 1) {
        int t = __shfl_up(v, off);
        if (lane >= off) v += t;
    }
    __shared__ int wsum[16];
    if (lane == 63) wsum[wid] = v;
    __syncthreads();
    if (wid == 0) {
        int w = (lane < 16) ? wsum[lane] : 0;
        #pragma unroll
        for (int off = 1; off < 16; off <<= 1) {
            int t = __shfl_up(w, off);
            if (lane >= off) w += t;
        }
        if (lane < 16) wsum[lane] = w;
    }
    __syncthreads();
    int waveoff = (wid > 0) ? wsum[wid - 1] : 0;
    int run = waveoff + v - s;
    for (int i = beg; i < end; ++i) {
        offsets[i] = run; cursor[i] = run;
        run += cnt[i];
    }
    if (tid == 1023) offsets[n] = run;
}

__global__ void fill_kernel(const int* __restrict__ src, const int* __restrict__ dst,
                            int* __restrict__ cursor, int* __restrict__ csr, int e) {
    int i = blockIdx.x * blockDim.x + threadIdx.x;
    if (i < e) {
        int p = atomicAdd(&cursor[dst[i]], 1);
        csr[p] = src[i];
    }
}

// ---------------- conversions ----------------

__global__ void convt_kernel(const float* __restrict__ W, unsigned short* __restrict__ Wt,
                             int K, int NCOL) {
    int i = blockIdx.x * blockDim.x + threadIdx.x;
    if (i < K * NCOL) {
        int k = i / NCOL, n = i - k * NCOL;
        Wt[(size_t)n * K + k] = f2bf(W[i]);
    }
}

__global__ void convx_kernel(const float* __restrict__ x, unsigned short* __restrict__ xb, int n4) {
    int i = blockIdx.x * blockDim.x + threadIdx.x;
    if (i < n4) {
        float4 v = ((const float4*)x)[i];
        ushort4 o;
        o.x = f2bf(v.x); o.y = f2bf(v.y); o.z = f2bf(v.z); o.w = f2bf(v.w);
        ((ushort4*)xb)[i] = o;
    }
}

// ---------------- bf16 MFMA GEMM: C[M,256] = A[M,K] @ W[K,256] ----------------
// MODE 0: +bias[col]   MODE 1: *dinv[row]

template <int MODE>
__global__ __launch_bounds__(256) void gemm_bf16(const unsigned short* __restrict__ A,
                                                 const unsigned short* __restrict__ Wt,
                                                 const float* __restrict__ aux,
                                                 unsigned short* __restrict__ C,
                                                 int M, int K) {
    __shared__ unsigned short As[128 * 32];   // [row][k] 8 KB
    __shared__ unsigned short Bs[128 * 32];   // [col][k] 8 KB
    const int tid  = threadIdx.x;
    const int lane = tid & 63;
    const int w    = tid >> 6;
    const int wr   = w >> 1, wc = w & 1;
    const int row0 = blockIdx.x * 128;
    const int col0 = blockIdx.y * 128;
    const int mlane = lane & 15, quad = lane >> 4;

    f32x4 acc[4][4];
    #pragma unroll
    for (int i = 0; i < 4; ++i)
        #pragma unroll
        for (int j = 0; j < 4; ++j) acc[i][j] = f32x4{0.f, 0.f, 0.f, 0.f};

    int cid0 = (0 * 4 + w) * 64 + lane;
    int cid1 = (1 * 4 + w) * 64 + lane;
    int r0 = cid0 >> 2, c0 = cid0 & 3;
    int r1 = cid1 >> 2, c1 = cid1 & 3;
    int rowA0 = row0 + r0; if (rowA0 >= M) rowA0 = M - 1;
    int rowA1 = row0 + r1; if (rowA1 >= M) rowA1 = M - 1;
    const unsigned short* gA0 = A + (size_t)rowA0 * K + c0 * 8;
    const unsigned short* gA1 = A + (size_t)rowA1 * K + c1 * 8;
    const unsigned short* gB0 = Wt + (size_t)(col0 + r0) * K + c0 * 8;
    const unsigned short* gB1 = Wt + (size_t)(col0 + r1) * K + c1 * 8;
    unsigned short* lA0 = &As[(0 * 4 + w) * 512];
    unsigned short* lA1 = &As[(1 * 4 + w) * 512];
    unsigned short* lB0 = &Bs[(0 * 4 + w) * 512];
    unsigned short* lB1 = &Bs[(1 * 4 + w) * 512];

    const int aoff = (lane >> 4) * 8;

    for (int k0 = 0; k0 < K; k0 += 32) {
        GL2LDS16(gA0 + k0, lA0);
        GL2LDS16(gA1 + k0, lA1);
        GL2LDS16(gB0 + k0, lB0);
        GL2LDS16(gB1 + k0, lB1);
        __syncthreads();
        bf16x8 af[4], bfv[4];
        #pragma unroll
        for (int i = 0; i < 4; ++i)
            af[i] = *(const bf16x8*)&As[(wr * 64 + i * 16 + mlane) * 32 + aoff];
        #pragma unroll
        for (int j = 0; j < 4; ++j)
            bfv[j] = *(const bf16x8*)&Bs[(wc * 64 + j * 16 + mlane) * 32 + aoff];
        #pragma unroll
        for (int i = 0; i < 4; ++i)
            #pragma unroll
            for (int j = 0; j < 4; ++j)
                acc[i][j] = __builtin_amdgcn_mfma_f32_16x16x32_bf16(af[i], bfv[j], acc[i][j], 0, 0, 0);
        __syncthreads();
    }

    float bj[4];
    if (MODE == 0) {
        #pragma unroll
        for (int j = 0; j < 4; ++j) bj[j] = aux[col0 + wc * 64 + j * 16 + mlane];
    }
    #pragma unroll
    for (int i = 0; i < 4; ++i) {
        #pragma unroll
        for (int r = 0; r < 4; ++r) {
            int grow = row0 + wr * 64 + i * 16 + quad * 4 + r;
            if (grow < M) {
                float d = (MODE == 1) ? aux[grow] : 0.f;
                #pragma unroll
                for (int j = 0; j < 4; ++j) {
                    int gcol = col0 + wc * 64 + j * 16 + mlane;
                    float v = acc[i][j][r];
                    v = (MODE == 0) ? (v + bj[j]) : (v * d);
                    C[(size_t)grow * 256 + gcol] = f2bf(v);
                }
            }
        }
    }
}

// ---------------- aggregation (bf16 gather, fp32 accumulate) ----------------

__global__ __launch_bounds__(256) void agg_kernel(const unsigned short* __restrict__ hs,
                                                  const int* __restrict__ offsets,
                                                  const int* __restrict__ csr,
                                                  const float* __restrict__ dinv,
                                                  const float* __restrict__ bias,
                                                  unsigned short* __restrict__ out, int n) {
    int node = blockIdx.x * 4 + (threadIdx.x >> 6);
    if (node >= n) return;
    int lane = threadIdx.x & 63;
    const ushort4* hs4 = (const ushort4*)hs;
    int beg = offsets[node], end = offsets[node + 1];
    ushort4 sv = hs4[(size_t)node * 64 + lane];
    float a0 = bf2f(sv.x), a1 = bf2f(sv.y), a2 = bf2f(sv.z), a3 = bf2f(sv.w);
    int e = beg;
    for (; e + 2 <= end; e += 2) {
        int s0 = csr[e], s1 = csr[e + 1];
        ushort4 v0 = hs4[(size_t)s0 * 64 + lane];
        ushort4 v1 = hs4[(size_t)s1 * 64 + lane];
        a0 += bf2f(v0.x) + bf2f(v1.x);
        a1 += bf2f(v0.y) + bf2f(v1.y);
        a2 += bf2f(v0.z) + bf2f(v1.z);
        a3 += bf2f(v0.w) + bf2f(v1.w);
    }
    if (e < end) {
        ushort4 v0 = hs4[(size_t)csr[e] * 64 + lane];
        a0 += bf2f(v0.x); a1 += bf2f(v0.y); a2 += bf2f(v0.z); a3 += bf2f(v0.w);
    }
    float d = dinv[node];
    float4 b = ((const float4*)bias)[lane];
    ushort4 r;
    r.x = f2bf(fmaxf(fmaf(a0, d, b.x), 0.f));
    r.y = f2bf(fmaxf(fmaf(a1, d, b.y), 0.f));
    r.z = f2bf(fmaxf(fmaf(a2, d, b.z), 0.f));
    r.w = f2bf(fmaxf(fmaf(a3, d, b.w), 0.f));
    ((ushort4*)out)[(size_t)node * 64 + lane] = r;
}

// ---------------- pooling stage 1: per-chunk partial sums -> atomics ----------------
// batch is sorted. Block b owns rows [b*chunk, min(n,(b+1)*chunk)). Thread = channel.
// Accumulate a register run while batch[i] is constant; flush once per graph boundary.

__global__ __launch_bounds__(256) void pool_partial_kernel(const unsigned short* __restrict__ h,
                                                           const int* __restrict__ batch,
                                                           float* __restrict__ sums,
                                                           int* __restrict__ counts,
                                                           int n, int chunk) {
    int beg = blockIdx.x * chunk;
    int end = beg + chunk; if (end > n) end = n;
    if (beg >= end) return;
    int c = threadIdx.x;
    int curg = batch[beg];
    float acc = 0.f;
    int runlen = 0;
    for (int i = beg; i < end; ++i) {
        int g = batch[i];
        if (g != curg) {
            atomicAdd(&sums[(size_t)curg * 256 + c], acc);
            if (c == 0) atomicAdd(&counts[curg], runlen);
            acc = 0.f; runlen = 0; curg = g;
        }
        acc += bf2f(h[(size_t)i * 256 + c]);
        ++runlen;
    }
    atomicAdd(&sums[(size_t)curg * 256 + c], acc);
    if (c == 0) atomicAdd(&counts[curg], runlen);
}

// ---------------- pooling stage 2: divide + 16-wide GEMV head ----------------

__global__ __launch_bounds__(256) void pool_final_kernel(const float* __restrict__ sums,
                                                         const int* __restrict__ counts,
                                                         const float* __restrict__ Wout,
                                                         const float* __restrict__ bout,
                                                         float* __restrict__ out) {
    __shared__ float pl[256];
    int g = blockIdx.x;
    int c = threadIdx.x;
    int cnt = counts[g];
    pl[c] = sums[(size_t)g * 256 + c] / (float)(cnt > 0 ? cnt : 1);
    __syncthreads();
    if (c < 16) {
        float o = bout[c];
        #pragma unroll 4
        for (int k = 0; k < 256; ++k) o = fmaf(pl[k], Wout[k * 16 + c], o);
        out[g * 16 + c] = o;
    }
}

// ---------------- launch ----------------

extern "C" void kernel_launch(void* const* d_in, const int* in_sizes, int n_in,
                              void* d_out, int out_size, void* d_ws, size_t ws_size,
                              hipStream_t stream) {
    const float* x     = (const float*)d_in[0];
    const int*   ei    = (const int*)d_in[1];
    const int*   batch = (const int*)d_in[2];
    const float* W_in  = (const float*)d_in[3];
    const float* b_in  = (const float*)d_in[4];
    const float* W1    = (const float*)d_in[5];
    const float* b1    = (const float*)d_in[6];
    const float* W2    = (const float*)d_in[7];
    const float* b2    = (const float*)d_in[8];
    const float* Wout  = (const float*)d_in[9];
    const float* bout  = (const float*)d_in[10];

    const int E = in_sizes[1] / 2;
    const int N = in_sizes[2];
    const int IN_DIM = in_sizes[0] / N;   // 128
    const int G = 128;
    const int* src = ei;
    const int* dst = ei + E;

    char* ws = (char*)d_ws;
    size_t off = 0;
    auto alloc = [&](size_t bytes) { size_t p = off; off += (bytes + 255) & ~(size_t)255; return p; };
    unsigned short* bufA = (unsigned short*)(ws + alloc((size_t)N * 256 * 2));
    unsigned short* bufB = (unsigned short*)(ws + alloc((size_t)N * 256 * 2));
    unsigned short* xb   = (unsigned short*)(ws + alloc((size_t)N * IN_DIM * 2));
    unsigned short* WtIn = (unsigned short*)(ws + alloc((size_t)IN_DIM * 256 * 2));
    unsigned short* Wt1  = (unsigned short*)(ws + alloc((size_t)256 * 256 * 2));
    unsigned short* Wt2  = (unsigned short*)(ws + alloc((size_t)256 * 256 * 2));
    int*   deg_cnt = (int*)(ws + alloc((size_t)N * 4));
    float* dinv    = (float*)(ws + alloc((size_t)N * 4));
    int*   offsets = (int*)(ws + alloc((size_t)(N + 1) * 4));
    int*   cursor  = (int*)(ws + alloc((size_t)N * 4));
    int*   csr     = (int*)(ws + alloc((size_t)E * 4));
    float* sums    = (float*)(ws + alloc((size_t)G * 256 * 4));
    int*   counts  = (int*)(ws + alloc((size_t)G * 4));
    (void)ws_size;

    // graph structure
    hipMemsetAsync(deg_cnt, 0, (size_t)N * 4, stream);
    hipMemsetAsync(sums, 0, (size_t)G * 256 * 4 + 256, stream);   // sums (+ counts: adjacent alloc)
    hipMemsetAsync(counts, 0, (size_t)G * 4, stream);
    count_kernel<<<(E + 255) / 256, 256, 0, stream>>>(dst, deg_cnt, E);
    dinv_kernel<<<(N + 255) / 256, 256, 0, stream>>>(deg_cnt, dinv, N);
    scan_kernel<<<1, 1024, 0, stream>>>(deg_cnt, offsets, cursor, N);
    fill_kernel<<<(E + 255) / 256, 256, 0, stream>>>(src, dst, cursor, csr, E);

    // bf16 conversions
    convt_kernel<<<(IN_DIM * 256 + 255) / 256, 256, 0, stream>>>(W_in, WtIn, IN_DIM, 256);
    convt_kernel<<<(256 * 256 + 255) / 256, 256, 0, stream>>>(W1, Wt1, 256, 256);
    convt_kernel<<<(256 * 256 + 255) / 256, 256, 0, stream>>>(W2, Wt2, 256, 256);
    convx_kernel<<<((N * IN_DIM / 4) + 255) / 256, 256, 0, stream>>>(x, xb, N * IN_DIM / 4);

    dim3 gg((N + 127) / 128, 2);
    gemm_bf16<0><<<gg, 256, 0, stream>>>(xb, WtIn, b_in, bufA, N, IN_DIM);
    gemm_bf16<1><<<gg, 256, 0, stream>>>(bufA, Wt1, dinv, bufB, N, 256);
    agg_kernel<<<(N + 3) / 4, 256, 0, stream>>>(bufB, offsets, csr, dinv, b1, bufA, N);
    gemm_bf16<1><<<gg, 256, 0, stream>>>(bufA, Wt2, dinv, bufB, N, 256);
    agg_kernel<<<(N + 3) / 4, 256, 0, stream>>>(bufB, offsets, csr, dinv, b2, bufA, N);

    // two-stage pool + head
    const int PBLOCKS = 400;
    int chunk = (N + PBLOCKS - 1) / PBLOCKS;
    pool_partial_kernel<<<PBLOCKS, 256, 0, stream>>>(bufA, batch, sums, counts, N, chunk);
    pool_final_kernel<<<G, 256, 0, stream>>>(sums, counts, Wout, bout, (float*)d_out);
}

// Round 4
// 441.559 us; speedup vs baseline: 1.9447x; 1.2217x over previous
//
#include <hip/hip_runtime.h>
#include <hip/hip_bf16.h>

typedef __attribute__((ext_vector_type(8))) short bf16x8;   // 8 bf16 in 4 VGPRs (MFMA A/B frag)
typedef __attribute__((ext_vector_type(4))) float f32x4;    // MFMA C/D frag

__device__ __forceinline__ unsigned short f2bf(float f) {   // RNE fp32->bf16
    unsigned u = __float_as_uint(f);
    u += 0x7fff + ((u >> 16) & 1);
    return (unsigned short)(u >> 16);
}
__device__ __forceinline__ float bf2f(unsigned short s) {
    return __uint_as_float(((unsigned)s) << 16);
}

#define GL2LDS16(g, l) __builtin_amdgcn_global_load_lds(                      \
        (const __attribute__((address_space(1))) void*)(g),                   \
        (__attribute__((address_space(3))) void*)(l), 16, 0, 0)

// ---------------- CSR build ----------------

__global__ void count_kernel(const int* __restrict__ dst, int* __restrict__ cnt, int e) {
    int i = blockIdx.x * blockDim.x + threadIdx.x;
    if (i < e) atomicAdd(&cnt[dst[i]], 1);
}

// stage 1: per-block (256-elem) sums, coalesced
__global__ __launch_bounds__(256) void block_sum_kernel(const int* __restrict__ cnt,
                                                        int* __restrict__ bsums, int n) {
    int tid = threadIdx.x;
    int i = blockIdx.x * 256 + tid;
    int v = (i < n) ? cnt[i] : 0;
    #pragma unroll
    for (int off = 32; off > 0; off >>= 1) v += __shfl_down(v, off);
    __shared__ int ws[4];
    if ((tid & 63) == 0) ws[tid >> 6] = v;
    __syncthreads();
    if (tid == 0) bsums[blockIdx.x] = ws[0] + ws[1] + ws[2] + ws[3];
}

// stage 2: exclusive scan of block sums (nb <= 256), single block
__global__ __launch_bounds__(256) void bsum_scan_kernel(int* __restrict__ bsums, int nb) {
    int tid = threadIdx.x;
    int lane = tid & 63, wid = tid >> 6;
    int v = (tid < nb) ? bsums[tid] : 0;
    int s = v;
    #pragma unroll
    for (int off = 1; off < 64; off <<= 1) {
        int t = __shfl_up(s, off);
        if (lane >= off) s += t;
    }
    __shared__ int ws[4];
    if (lane == 63) ws[wid] = s;
    __syncthreads();
    int wo = 0;
    #pragma unroll
    for (int k = 0; k < 4; ++k) wo += (k < wid) ? ws[k] : 0;
    if (tid < nb) bsums[tid] = wo + s - v;   // exclusive
}

// stage 3: in-block exclusive scan + block offset -> offsets/cursor; fused dinv
__global__ __launch_bounds__(256) void scatter_scan_kernel(const int* __restrict__ cnt,
                                                           const int* __restrict__ bsums,
                                                           int* __restrict__ offsets,
                                                           int* __restrict__ cursor,
                                                           float* __restrict__ dinv, int n) {
    int tid = threadIdx.x;
    int lane = tid & 63, wid = tid >> 6;
    int i = blockIdx.x * 256 + tid;
    int v = (i < n) ? cnt[i] : 0;
    int s = v;
    #pragma unroll
    for (int off = 1; off < 64; off <<= 1) {
        int t = __shfl_up(s, off);
        if (lane >= off) s += t;
    }
    __shared__ int ws[4];
    if (lane == 63) ws[wid] = s;
    __syncthreads();
    int wo = 0;
    #pragma unroll
    for (int k = 0; k < 4; ++k) wo += (k < wid) ? ws[k] : 0;
    int excl = bsums[blockIdx.x] + wo + s - v;
    if (i <= n) { offsets[i] = excl; }
    if (i < n) {
        cursor[i] = excl;
        dinv[i] = rsqrtf((float)v + 1.0f);
    }
}

__global__ void fill_kernel(const int* __restrict__ src, const int* __restrict__ dst,
                            int* __restrict__ cursor, int* __restrict__ csr, int e) {
    int i = blockIdx.x * blockDim.x + threadIdx.x;
    if (i < e) {
        int p = atomicAdd(&cursor[dst[i]], 1);
        csr[p] = src[i];
    }
}

// ---------------- conversions ----------------

// three weight transposes in one launch: W[K][256] fp32 -> Wt[256][K] bf16
__global__ void convt3_kernel(const float* __restrict__ Wa, unsigned short* __restrict__ Ta, int Ka,
                              const float* __restrict__ Wb, unsigned short* __restrict__ Tb, int Kb,
                              const float* __restrict__ Wc, unsigned short* __restrict__ Tc, int Kc) {
    int i = blockIdx.x * blockDim.x + threadIdx.x;
    int na = Ka * 256, nb = Kb * 256, nc = Kc * 256;
    const float* W; unsigned short* T; int K, j;
    if (i < na)            { W = Wa; T = Ta; K = Ka; j = i; }
    else if (i < na + nb)  { W = Wb; T = Tb; K = Kb; j = i - na; }
    else if (i < na + nb + nc) { W = Wc; T = Tc; K = Kc; j = i - na - nb; }
    else return;
    int k = j >> 8, n = j & 255;
    T[(size_t)n * K + k] = f2bf(W[j]);
}

__global__ void convx_kernel(const float* __restrict__ x, unsigned short* __restrict__ xb, int n4) {
    int i = blockIdx.x * blockDim.x + threadIdx.x;
    if (i < n4) {
        float4 v = ((const float4*)x)[i];
        ushort4 o;
        o.x = f2bf(v.x); o.y = f2bf(v.y); o.z = f2bf(v.z); o.w = f2bf(v.w);
        ((ushort4*)xb)[i] = o;
    }
}

// ---------------- bf16 MFMA GEMM: C[M,256] = A[M,K] @ W[K,256] ----------------
// MODE 0: +bias[col]   MODE 1: *dinv[row]

template <int MODE>
__global__ __launch_bounds__(256) void gemm_bf16(const unsigned short* __restrict__ A,
                                                 const unsigned short* __restrict__ Wt,
                                                 const float* __restrict__ aux,
                                                 unsigned short* __restrict__ C,
                                                 int M, int K) {
    __shared__ unsigned short As[128 * 32];   // [row][k] 8 KB
    __shared__ unsigned short Bs[128 * 32];   // [col][k] 8 KB
    const int tid  = threadIdx.x;
    const int lane = tid & 63;
    const int w    = tid >> 6;
    const int wr   = w >> 1, wc = w & 1;
    const int row0 = blockIdx.x * 128;
    const int col0 = blockIdx.y * 128;
    const int mlane = lane & 15, quad = lane >> 4;

    f32x4 acc[4][4];
    #pragma unroll
    for (int i = 0; i < 4; ++i)
        #pragma unroll
        for (int j = 0; j < 4; ++j) acc[i][j] = f32x4{0.f, 0.f, 0.f, 0.f};

    int cid0 = (0 * 4 + w) * 64 + lane;
    int cid1 = (1 * 4 + w) * 64 + lane;
    int r0 = cid0 >> 2, c0 = cid0 & 3;
    int r1 = cid1 >> 2, c1 = cid1 & 3;
    int rowA0 = row0 + r0; if (rowA0 >= M) rowA0 = M - 1;
    int rowA1 = row0 + r1; if (rowA1 >= M) rowA1 = M - 1;
    const unsigned short* gA0 = A + (size_t)rowA0 * K + c0 * 8;
    const unsigned short* gA1 = A + (size_t)rowA1 * K + c1 * 8;
    const unsigned short* gB0 = Wt + (size_t)(col0 + r0) * K + c0 * 8;
    const unsigned short* gB1 = Wt + (size_t)(col0 + r1) * K + c1 * 8;
    unsigned short* lA0 = &As[(0 * 4 + w) * 512];
    unsigned short* lA1 = &As[(1 * 4 + w) * 512];
    unsigned short* lB0 = &Bs[(0 * 4 + w) * 512];
    unsigned short* lB1 = &Bs[(1 * 4 + w) * 512];

    const int aoff = (lane >> 4) * 8;

    for (int k0 = 0; k0 < K; k0 += 32) {
        GL2LDS16(gA0 + k0, lA0);
        GL2LDS16(gA1 + k0, lA1);
        GL2LDS16(gB0 + k0, lB0);
        GL2LDS16(gB1 + k0, lB1);
        __syncthreads();
        bf16x8 af[4], bfv[4];
        #pragma unroll
        for (int i = 0; i < 4; ++i)
            af[i] = *(const bf16x8*)&As[(wr * 64 + i * 16 + mlane) * 32 + aoff];
        #pragma unroll
        for (int j = 0; j < 4; ++j)
            bfv[j] = *(const bf16x8*)&Bs[(wc * 64 + j * 16 + mlane) * 32 + aoff];
        #pragma unroll
        for (int i = 0; i < 4; ++i)
            #pragma unroll
            for (int j = 0; j < 4; ++j)
                acc[i][j] = __builtin_amdgcn_mfma_f32_16x16x32_bf16(af[i], bfv[j], acc[i][j], 0, 0, 0);
        __syncthreads();
    }

    float bj[4];
    if (MODE == 0) {
        #pragma unroll
        for (int j = 0; j < 4; ++j) bj[j] = aux[col0 + wc * 64 + j * 16 + mlane];
    }
    #pragma unroll
    for (int i = 0; i < 4; ++i) {
        #pragma unroll
        for (int r = 0; r < 4; ++r) {
            int grow = row0 + wr * 64 + i * 16 + quad * 4 + r;
            if (grow < M) {
                float d = (MODE == 1) ? aux[grow] : 0.f;
                #pragma unroll
                for (int j = 0; j < 4; ++j) {
                    int gcol = col0 + wc * 64 + j * 16 + mlane;
                    float v = acc[i][j][r];
                    v = (MODE == 0) ? (v + bj[j]) : (v * d);
                    C[(size_t)grow * 256 + gcol] = f2bf(v);
                }
            }
        }
    }
}

// ---------------- aggregation (bf16 gather, fp32 accumulate) ----------------

__global__ __launch_bounds__(256) void agg_kernel(const unsigned short* __restrict__ hs,
                                                  const int* __restrict__ offsets,
                                                  const int* __restrict__ csr,
                                                  const float* __restrict__ dinv,
                                                  const float* __restrict__ bias,
                                                  unsigned short* __restrict__ out, int n) {
    int node = blockIdx.x * 4 + (threadIdx.x >> 6);
    if (node >= n) return;
    int lane = threadIdx.x & 63;
    const ushort4* hs4 = (const ushort4*)hs;
    int beg = offsets[node], end = offsets[node + 1];
    ushort4 sv = hs4[(size_t)node * 64 + lane];
    float a0 = bf2f(sv.x), a1 = bf2f(sv.y), a2 = bf2f(sv.z), a3 = bf2f(sv.w);
    int e = beg;
    for (; e + 2 <= end; e += 2) {
        int s0 = csr[e], s1 = csr[e + 1];
        ushort4 v0 = hs4[(size_t)s0 * 64 + lane];
        ushort4 v1 = hs4[(size_t)s1 * 64 + lane];
        a0 += bf2f(v0.x) + bf2f(v1.x);
        a1 += bf2f(v0.y) + bf2f(v1.y);
        a2 += bf2f(v0.z) + bf2f(v1.z);
        a3 += bf2f(v0.w) + bf2f(v1.w);
    }
    if (e < end) {
        ushort4 v0 = hs4[(size_t)csr[e] * 64 + lane];
        a0 += bf2f(v0.x); a1 += bf2f(v0.y); a2 += bf2f(v0.z); a3 += bf2f(v0.w);
    }
    float d = dinv[node];
    float4 b = ((const float4*)bias)[lane];
    ushort4 r;
    r.x = f2bf(fmaxf(fmaf(a0, d, b.x), 0.f));
    r.y = f2bf(fmaxf(fmaf(a1, d, b.y), 0.f));
    r.z = f2bf(fmaxf(fmaf(a2, d, b.z), 0.f));
    r.w = f2bf(fmaxf(fmaf(a3, d, b.w), 0.f));
    ((ushort4*)out)[(size_t)node * 64 + lane] = r;
}

// ---------------- pooling stage 1: per-chunk partial sums -> atomics ----------------

__global__ __launch_bounds__(256) void pool_partial_kernel(const unsigned short* __restrict__ h,
                                                           const int* __restrict__ batch,
                                                           float* __restrict__ sums,
                                                           int* __restrict__ counts,
                                                           int n, int chunk) {
    int beg = blockIdx.x * chunk;
    int end = beg + chunk; if (end > n) end = n;
    if (beg >= end) return;
    int c = threadIdx.x;
    int curg = batch[beg];
    float acc = 0.f;
    int runlen = 0;
    for (int i = beg; i < end; ++i) {
        int g = batch[i];
        if (g != curg) {
            atomicAdd(&sums[(size_t)curg * 256 + c], acc);
            if (c == 0) atomicAdd(&counts[curg], runlen);
            acc = 0.f; runlen = 0; curg = g;
        }
        acc += bf2f(h[(size_t)i * 256 + c]);
        ++runlen;
    }
    atomicAdd(&sums[(size_t)curg * 256 + c], acc);
    if (c == 0) atomicAdd(&counts[curg], runlen);
}

// ---------------- pooling stage 2: divide + 16-wide GEMV head ----------------

__global__ __launch_bounds__(256) void pool_final_kernel(const float* __restrict__ sums,
                                                         const int* __restrict__ counts,
                                                         const float* __restrict__ Wout,
                                                         const float* __restrict__ bout,
                                                         float* __restrict__ out) {
    __shared__ float pl[256];
    int g = blockIdx.x;
    int c = threadIdx.x;
    int cnt = counts[g];
    pl[c] = sums[(size_t)g * 256 + c] / (float)(cnt > 0 ? cnt : 1);
    __syncthreads();
    if (c < 16) {
        float o = bout[c];
        #pragma unroll 4
        for (int k = 0; k < 256; ++k) o = fmaf(pl[k], Wout[k * 16 + c], o);
        out[g * 16 + c] = o;
    }
}

// ---------------- launch ----------------

extern "C" void kernel_launch(void* const* d_in, const int* in_sizes, int n_in,
                              void* d_out, int out_size, void* d_ws, size_t ws_size,
                              hipStream_t stream) {
    const float* x     = (const float*)d_in[0];
    const int*   ei    = (const int*)d_in[1];
    const int*   batch = (const int*)d_in[2];
    const float* W_in  = (const float*)d_in[3];
    const float* b_in  = (const float*)d_in[4];
    const float* W1    = (const float*)d_in[5];
    const float* b1    = (const float*)d_in[6];
    const float* W2    = (const float*)d_in[7];
    const float* b2    = (const float*)d_in[8];
    const float* Wout  = (const float*)d_in[9];
    const float* bout  = (const float*)d_in[10];

    const int E = in_sizes[1] / 2;
    const int N = in_sizes[2];
    const int IN_DIM = in_sizes[0] / N;   // 128
    const int G = 128;
    const int* src = ei;
    const int* dst = ei + E;

    char* ws = (char*)d_ws;
    size_t off = 0;
    auto alloc = [&](size_t bytes) { size_t p = off; off += (bytes + 255) & ~(size_t)255; return p; };
    unsigned short* bufA = (unsigned short*)(ws + alloc((size_t)N * 256 * 2));
    unsigned short* bufB = (unsigned short*)(ws + alloc((size_t)N * 256 * 2));
    unsigned short* xb   = (unsigned short*)(ws + alloc((size_t)N * IN_DIM * 2));
    unsigned short* WtIn = (unsigned short*)(ws + alloc((size_t)IN_DIM * 256 * 2));
    unsigned short* Wt1  = (unsigned short*)(ws + alloc((size_t)256 * 256 * 2));
    unsigned short* Wt2  = (unsigned short*)(ws + alloc((size_t)256 * 256 * 2));
    int*   deg_cnt = (int*)(ws + alloc((size_t)N * 4));
    float* dinv    = (float*)(ws + alloc((size_t)N * 4));
    int*   offsets = (int*)(ws + alloc((size_t)(N + 1) * 4));
    int*   cursor  = (int*)(ws + alloc((size_t)N * 4));
    int*   csr     = (int*)(ws + alloc((size_t)E * 4));
    int*   bsums   = (int*)(ws + alloc((size_t)256 * 4));
    float* sums    = (float*)(ws + alloc((size_t)G * 256 * 4));
    int*   counts  = (int*)(ws + alloc((size_t)G * 4));
    (void)ws_size;

    const int NB = (N + 255) / 256;          // scan blocks
    const int NB1 = (N + 1 + 255) / 256;     // covers offsets[N]

    // graph structure
    hipMemsetAsync(deg_cnt, 0, (size_t)N * 4, stream);
    hipMemsetAsync(sums, 0, (size_t)G * 256 * 4, stream);
    hipMemsetAsync(counts, 0, (size_t)G * 4, stream);
    count_kernel<<<(E + 255) / 256, 256, 0, stream>>>(dst, deg_cnt, E);
    block_sum_kernel<<<NB, 256, 0, stream>>>(deg_cnt, bsums, N);
    bsum_scan_kernel<<<1, 256, 0, stream>>>(bsums, NB);
    scatter_scan_kernel<<<NB1, 256, 0, stream>>>(deg_cnt, bsums, offsets, cursor, dinv, N);
    fill_kernel<<<(E + 255) / 256, 256, 0, stream>>>(src, dst, cursor, csr, E);

    // bf16 conversions
    convt3_kernel<<<(IN_DIM * 256 + 2 * 256 * 256 + 255) / 256, 256, 0, stream>>>(
        W_in, WtIn, IN_DIM, W1, Wt1, 256, W2, Wt2, 256);
    convx_kernel<<<((N * IN_DIM / 4) + 255) / 256, 256, 0, stream>>>(x, xb, N * IN_DIM / 4);

    dim3 gg((N + 127) / 128, 2);
    gemm_bf16<0><<<gg, 256, 0, stream>>>(xb, WtIn, b_in, bufA, N, IN_DIM);
    gemm_bf16<1><<<gg, 256, 0, stream>>>(bufA, Wt1, dinv, bufB, N, 256);
    agg_kernel<<<(N + 3) / 4, 256, 0, stream>>>(bufB, offsets, csr, dinv, b1, bufA, N);
    gemm_bf16<1><<<gg, 256, 0, stream>>>(bufA, Wt2, dinv, bufB, N, 256);
    agg_kernel<<<(N + 3) / 4, 256, 0, stream>>>(bufB, offsets, csr, dinv, b2, bufA, N);

    // two-stage pool + head
    const int PBLOCKS = 400;
    int chunk = (N + PBLOCKS - 1) / PBLOCKS;
    pool_partial_kernel<<<PBLOCKS, 256, 0, stream>>>(bufA, batch, sums, counts, N, chunk);
    pool_final_kernel<<<G, 256, 0, stream>>>(sums, counts, Wout, bout, (float*)d_out);
}

// Round 5
// 414.772 us; speedup vs baseline: 2.0703x; 1.0646x over previous
//
#include <hip/hip_runtime.h>
#include <hip/hip_bf16.h>

typedef __attribute__((ext_vector_type(8))) short bf16x8;   // 8 bf16 in 4 VGPRs (MFMA A/B frag)
typedef __attribute__((ext_vector_type(4))) float f32x4;    // MFMA C/D frag

__device__ __forceinline__ unsigned short f2bf(float f) {   // RNE fp32->bf16
    unsigned u = __float_as_uint(f);
    u += 0x7fff + ((u >> 16) & 1);
    return (unsigned short)(u >> 16);
}
__device__ __forceinline__ float bf2f(unsigned short s) {
    return __uint_as_float(((unsigned)s) << 16);
}

#define GL2LDS16(g, l) __builtin_amdgcn_global_load_lds(                      \
        (const __attribute__((address_space(1))) void*)(g),                   \
        (__attribute__((address_space(3))) void*)(l), 16, 0, 0)

// ---------------- fused setup: degree count + weight transposes + x->bf16 ----------------
// block ranges: [0,CB) count | [CB,CB+TB) convt x3 | [CB+TB,...) convx

__global__ __launch_bounds__(256) void fused_misc_kernel(
        const int* __restrict__ dst, int* __restrict__ cnt, int e,
        const float* __restrict__ Wa, unsigned short* __restrict__ Ta, int Ka,
        const float* __restrict__ Wb, unsigned short* __restrict__ Tb,
        const float* __restrict__ Wc, unsigned short* __restrict__ Tc,
        const float* __restrict__ x, unsigned short* __restrict__ xb, int n4,
        int CB, int TB) {
    int b = blockIdx.x;
    if (b < CB) {
        int i = b * 256 + threadIdx.x;
        if (i < e) atomicAdd(&cnt[dst[i]], 1);
    } else if (b < CB + TB) {
        int i = (b - CB) * 256 + threadIdx.x;
        int na = Ka * 256, nb = 256 * 256;
        if (i < na) {
            int k = i >> 8, n = i & 255;
            Ta[(size_t)n * Ka + k] = f2bf(Wa[i]);
        } else if (i < na + nb) {
            int j = i - na; int k = j >> 8, n = j & 255;
            Tb[(size_t)n * 256 + k] = f2bf(Wb[j]);
        } else if (i < na + 2 * nb) {
            int j = i - na - nb; int k = j >> 8, n = j & 255;
            Tc[(size_t)n * 256 + k] = f2bf(Wc[j]);
        }
    } else {
        int i = (b - CB - TB) * 256 + threadIdx.x;
        if (i < n4) {
            float4 v = ((const float4*)x)[i];
            ushort4 o;
            o.x = f2bf(v.x); o.y = f2bf(v.y); o.z = f2bf(v.z); o.w = f2bf(v.w);
            ((ushort4*)xb)[i] = o;
        }
    }
}

// ---------------- CSR scan (3-stage) ----------------

__global__ __launch_bounds__(256) void block_sum_kernel(const int* __restrict__ cnt,
                                                        int* __restrict__ bsums, int n) {
    int tid = threadIdx.x;
    int i = blockIdx.x * 256 + tid;
    int v = (i < n) ? cnt[i] : 0;
    #pragma unroll
    for (int off = 32; off > 0; off >>= 1) v += __shfl_down(v, off);
    __shared__ int ws[4];
    if ((tid & 63) == 0) ws[tid >> 6] = v;
    __syncthreads();
    if (tid == 0) bsums[blockIdx.x] = ws[0] + ws[1] + ws[2] + ws[3];
}

__global__ __launch_bounds__(256) void bsum_scan_kernel(int* __restrict__ bsums, int nb) {
    int tid = threadIdx.x;
    int lane = tid & 63, wid = tid >> 6;
    int v = (tid < nb) ? bsums[tid] : 0;
    int s = v;
    #pragma unroll
    for (int off = 1; off < 64; off <<= 1) {
        int t = __shfl_up(s, off);
        if (lane >= off) s += t;
    }
    __shared__ int ws[4];
    if (lane == 63) ws[wid] = s;
    __syncthreads();
    int wo = 0;
    #pragma unroll
    for (int k = 0; k < 4; ++k) wo += (k < wid) ? ws[k] : 0;
    if (tid < nb) bsums[tid] = wo + s - v;   // exclusive
}

__global__ __launch_bounds__(256) void scatter_scan_kernel(const int* __restrict__ cnt,
                                                           const int* __restrict__ bsums,
                                                           int* __restrict__ offsets,
                                                           int* __restrict__ cursor,
                                                           float* __restrict__ dinv, int n) {
    int tid = threadIdx.x;
    int lane = tid & 63, wid = tid >> 6;
    int i = blockIdx.x * 256 + tid;
    int v = (i < n) ? cnt[i] : 0;
    int s = v;
    #pragma unroll
    for (int off = 1; off < 64; off <<= 1) {
        int t = __shfl_up(s, off);
        if (lane >= off) s += t;
    }
    __shared__ int ws[4];
    if (lane == 63) ws[wid] = s;
    __syncthreads();
    int wo = 0;
    #pragma unroll
    for (int k = 0; k < 4; ++k) wo += (k < wid) ? ws[k] : 0;
    int excl = bsums[blockIdx.x] + wo + s - v;
    if (i <= n) { offsets[i] = excl; }
    if (i < n) {
        cursor[i] = excl;
        dinv[i] = rsqrtf((float)v + 1.0f);
    }
}

__global__ void fill_kernel(const int* __restrict__ src, const int* __restrict__ dst,
                            int* __restrict__ cursor, int* __restrict__ csr, int e) {
    int i = blockIdx.x * blockDim.x + threadIdx.x;
    if (i < e) {
        int p = atomicAdd(&cursor[dst[i]], 1);
        csr[p] = src[i];
    }
}

// ---------------- bf16 MFMA GEMM: C[M,256] = A[M,K] @ W[K,256] ----------------
// MODE 0: +bias[col]   MODE 1: *dinv[row]

template <int MODE>
__global__ __launch_bounds__(256) void gemm_bf16(const unsigned short* __restrict__ A,
                                                 const unsigned short* __restrict__ Wt,
                                                 const float* __restrict__ aux,
                                                 unsigned short* __restrict__ C,
                                                 int M, int K) {
    __shared__ unsigned short As[128 * 32];   // [row][k] 8 KB
    __shared__ unsigned short Bs[128 * 32];   // [col][k] 8 KB
    const int tid  = threadIdx.x;
    const int lane = tid & 63;
    const int w    = tid >> 6;
    const int wr   = w >> 1, wc = w & 1;
    const int row0 = blockIdx.x * 128;
    const int col0 = blockIdx.y * 128;
    const int mlane = lane & 15, quad = lane >> 4;

    f32x4 acc[4][4];
    #pragma unroll
    for (int i = 0; i < 4; ++i)
        #pragma unroll
        for (int j = 0; j < 4; ++j) acc[i][j] = f32x4{0.f, 0.f, 0.f, 0.f};

    int cid0 = (0 * 4 + w) * 64 + lane;
    int cid1 = (1 * 4 + w) * 64 + lane;
    int r0 = cid0 >> 2, c0 = cid0 & 3;
    int r1 = cid1 >> 2, c1 = cid1 & 3;
    int rowA0 = row0 + r0; if (rowA0 >= M) rowA0 = M - 1;
    int rowA1 = row0 + r1; if (rowA1 >= M) rowA1 = M - 1;
    const unsigned short* gA0 = A + (size_t)rowA0 * K + c0 * 8;
    const unsigned short* gA1 = A + (size_t)rowA1 * K + c1 * 8;
    const unsigned short* gB0 = Wt + (size_t)(col0 + r0) * K + c0 * 8;
    const unsigned short* gB1 = Wt + (size_t)(col0 + r1) * K + c1 * 8;
    unsigned short* lA0 = &As[(0 * 4 + w) * 512];
    unsigned short* lA1 = &As[(1 * 4 + w) * 512];
    unsigned short* lB0 = &Bs[(0 * 4 + w) * 512];
    unsigned short* lB1 = &Bs[(1 * 4 + w) * 512];

    const int aoff = (lane >> 4) * 8;

    for (int k0 = 0; k0 < K; k0 += 32) {
        GL2LDS16(gA0 + k0, lA0);
        GL2LDS16(gA1 + k0, lA1);
        GL2LDS16(gB0 + k0, lB0);
        GL2LDS16(gB1 + k0, lB1);
        __syncthreads();
        bf16x8 af[4], bfv[4];
        #pragma unroll
        for (int i = 0; i < 4; ++i)
            af[i] = *(const bf16x8*)&As[(wr * 64 + i * 16 + mlane) * 32 + aoff];
        #pragma unroll
        for (int j = 0; j < 4; ++j)
            bfv[j] = *(const bf16x8*)&Bs[(wc * 64 + j * 16 + mlane) * 32 + aoff];
        #pragma unroll
        for (int i = 0; i < 4; ++i)
            #pragma unroll
            for (int j = 0; j < 4; ++j)
                acc[i][j] = __builtin_amdgcn_mfma_f32_16x16x32_bf16(af[i], bfv[j], acc[i][j], 0, 0, 0);
        __syncthreads();
    }

    float bj[4];
    if (MODE == 0) {
        #pragma unroll
        for (int j = 0; j < 4; ++j) bj[j] = aux[col0 + wc * 64 + j * 16 + mlane];
    }
    #pragma unroll
    for (int i = 0; i < 4; ++i) {
        #pragma unroll
        for (int r = 0; r < 4; ++r) {
            int grow = row0 + wr * 64 + i * 16 + quad * 4 + r;
            if (grow < M) {
                float d = (MODE == 1) ? aux[grow] : 0.f;
                #pragma unroll
                for (int j = 0; j < 4; ++j) {
                    int gcol = col0 + wc * 64 + j * 16 + mlane;
                    float v = acc[i][j][r];
                    v = (MODE == 0) ? (v + bj[j]) : (v * d);
                    C[(size_t)grow * 256 + gcol] = f2bf(v);
                }
            }
        }
    }
}

// ---------------- aggregation v2: index broadcast + 8-deep gather MLP ----------------
// out[n] = relu(dinv[n]*(sum_{e->n} hs[src] + hs[n]) + b), hs/out bf16, fp32 accum.
// Lane L pre-loads csr[e+L]; __shfl broadcasts (readlane -> SGPR base gathers).

__global__ __launch_bounds__(256) void agg_kernel(const unsigned short* __restrict__ hs,
                                                  const int* __restrict__ offsets,
                                                  const int* __restrict__ csr,
                                                  const float* __restrict__ dinv,
                                                  const float* __restrict__ bias,
                                                  unsigned short* __restrict__ out, int n) {
    int node = blockIdx.x * 4 + (threadIdx.x >> 6);
    if (node >= n) return;
    int lane = threadIdx.x & 63;
    const ushort4* hs4 = (const ushort4*)hs;
    int beg = offsets[node], end = offsets[node + 1];
    ushort4 sv = hs4[(size_t)node * 64 + lane];
    float a0 = bf2f(sv.x), a1 = bf2f(sv.y), a2 = bf2f(sv.z), a3 = bf2f(sv.w);
    float c0 = 0.f, c1 = 0.f, c2 = 0.f, c3 = 0.f;

    int e = beg;
    while (e < end) {
        int cnt = end - e; if (cnt > 64) cnt = 64;
        int myi = (lane < cnt) ? csr[e + lane] : 0;
        int j = 0;
        for (; j + 8 <= cnt; j += 8) {
            int s0 = __shfl(myi, j + 0), s1 = __shfl(myi, j + 1);
            int s2 = __shfl(myi, j + 2), s3 = __shfl(myi, j + 3);
            int s4 = __shfl(myi, j + 4), s5 = __shfl(myi, j + 5);
            int s6 = __shfl(myi, j + 6), s7 = __shfl(myi, j + 7);
            ushort4 v0 = hs4[(size_t)s0 * 64 + lane];
            ushort4 v1 = hs4[(size_t)s1 * 64 + lane];
            ushort4 v2 = hs4[(size_t)s2 * 64 + lane];
            ushort4 v3 = hs4[(size_t)s3 * 64 + lane];
            ushort4 v4 = hs4[(size_t)s4 * 64 + lane];
            ushort4 v5 = hs4[(size_t)s5 * 64 + lane];
            ushort4 v6 = hs4[(size_t)s6 * 64 + lane];
            ushort4 v7 = hs4[(size_t)s7 * 64 + lane];
            a0 += bf2f(v0.x) + bf2f(v1.x) + bf2f(v2.x) + bf2f(v3.x);
            a1 += bf2f(v0.y) + bf2f(v1.y) + bf2f(v2.y) + bf2f(v3.y);
            a2 += bf2f(v0.z) + bf2f(v1.z) + bf2f(v2.z) + bf2f(v3.z);
            a3 += bf2f(v0.w) + bf2f(v1.w) + bf2f(v2.w) + bf2f(v3.w);
            c0 += bf2f(v4.x) + bf2f(v5.x) + bf2f(v6.x) + bf2f(v7.x);
            c1 += bf2f(v4.y) + bf2f(v5.y) + bf2f(v6.y) + bf2f(v7.y);
            c2 += bf2f(v4.z) + bf2f(v5.z) + bf2f(v6.z) + bf2f(v7.z);
            c3 += bf2f(v4.w) + bf2f(v5.w) + bf2f(v6.w) + bf2f(v7.w);
        }
        for (; j < cnt; ++j) {
            int s = __shfl(myi, j);
            ushort4 v = hs4[(size_t)s * 64 + lane];
            a0 += bf2f(v.x); a1 += bf2f(v.y); a2 += bf2f(v.z); a3 += bf2f(v.w);
        }
        e += cnt;
    }
    a0 += c0; a1 += c1; a2 += c2; a3 += c3;

    float d = dinv[node];
    float4 b = ((const float4*)bias)[lane];
    ushort4 r;
    r.x = f2bf(fmaxf(fmaf(a0, d, b.x), 0.f));
    r.y = f2bf(fmaxf(fmaf(a1, d, b.y), 0.f));
    r.z = f2bf(fmaxf(fmaf(a2, d, b.z), 0.f));
    r.w = f2bf(fmaxf(fmaf(a3, d, b.w), 0.f));
    ((ushort4*)out)[(size_t)node * 64 + lane] = r;
}

// ---------------- pooling stage 1: per-chunk partial sums -> atomics ----------------

__global__ __launch_bounds__(256) void pool_partial_kernel(const unsigned short* __restrict__ h,
                                                           const int* __restrict__ batch,
                                                           float* __restrict__ sums,
                                                           int* __restrict__ counts,
                                                           int n, int chunk) {
    int beg = blockIdx.x * chunk;
    int end = beg + chunk; if (end > n) end = n;
    if (beg >= end) return;
    int c = threadIdx.x;
    int curg = batch[beg];
    float acc = 0.f;
    int runlen = 0;
    for (int i = beg; i < end; ++i) {
        int g = batch[i];
        if (g != curg) {
            atomicAdd(&sums[(size_t)curg * 256 + c], acc);
            if (c == 0) atomicAdd(&counts[curg], runlen);
            acc = 0.f; runlen = 0; curg = g;
        }
        acc += bf2f(h[(size_t)i * 256 + c]);
        ++runlen;
    }
    atomicAdd(&sums[(size_t)curg * 256 + c], acc);
    if (c == 0) atomicAdd(&counts[curg], runlen);
}

// ---------------- pooling stage 2: divide + 16-wide GEMV head ----------------

__global__ __launch_bounds__(256) void pool_final_kernel(const float* __restrict__ sums,
                                                         const int* __restrict__ counts,
                                                         const float* __restrict__ Wout,
                                                         const float* __restrict__ bout,
                                                         float* __restrict__ out) {
    __shared__ float pl[256];
    int g = blockIdx.x;
    int c = threadIdx.x;
    int cnt = counts[g];
    pl[c] = sums[(size_t)g * 256 + c] / (float)(cnt > 0 ? cnt : 1);
    __syncthreads();
    if (c < 16) {
        float o = bout[c];
        #pragma unroll 4
        for (int k = 0; k < 256; ++k) o = fmaf(pl[k], Wout[k * 16 + c], o);
        out[g * 16 + c] = o;
    }
}

// ---------------- launch ----------------

extern "C" void kernel_launch(void* const* d_in, const int* in_sizes, int n_in,
                              void* d_out, int out_size, void* d_ws, size_t ws_size,
                              hipStream_t stream) {
    const float* x     = (const float*)d_in[0];
    const int*   ei    = (const int*)d_in[1];
    const int*   batch = (const int*)d_in[2];
    const float* W_in  = (const float*)d_in[3];
    const float* b_in  = (const float*)d_in[4];
    const float* W1    = (const float*)d_in[5];
    const float* b1    = (const float*)d_in[6];
    const float* W2    = (const float*)d_in[7];
    const float* b2    = (const float*)d_in[8];
    const float* Wout  = (const float*)d_in[9];
    const float* bout  = (const float*)d_in[10];

    const int E = in_sizes[1] / 2;
    const int N = in_sizes[2];
    const int IN_DIM = in_sizes[0] / N;   // 128
    const int G = 128;
    const int* src = ei;
    const int* dst = ei + E;

    char* ws = (char*)d_ws;
    size_t off = 0;
    auto alloc = [&](size_t bytes) { size_t p = off; off += (bytes + 255) & ~(size_t)255; return p; };
    unsigned short* bufA = (unsigned short*)(ws + alloc((size_t)N * 256 * 2));
    unsigned short* bufB = (unsigned short*)(ws + alloc((size_t)N * 256 * 2));
    unsigned short* xb   = (unsigned short*)(ws + alloc((size_t)N * IN_DIM * 2));
    unsigned short* WtIn = (unsigned short*)(ws + alloc((size_t)IN_DIM * 256 * 2));
    unsigned short* Wt1  = (unsigned short*)(ws + alloc((size_t)256 * 256 * 2));
    unsigned short* Wt2  = (unsigned short*)(ws + alloc((size_t)256 * 256 * 2));
    // zero-init region: deg_cnt + sums + counts contiguous -> ONE memset
    size_t zbeg = off;
    int*   deg_cnt = (int*)(ws + alloc((size_t)N * 4));
    float* sums    = (float*)(ws + alloc((size_t)G * 256 * 4));
    int*   counts  = (int*)(ws + alloc((size_t)G * 4));
    size_t zend = off;
    float* dinv    = (float*)(ws + alloc((size_t)N * 4));
    int*   offsets = (int*)(ws + alloc((size_t)(N + 1) * 4));
    int*   cursor  = (int*)(ws + alloc((size_t)N * 4));
    int*   csr     = (int*)(ws + alloc((size_t)E * 4));
    int*   bsums   = (int*)(ws + alloc((size_t)256 * 4));
    (void)ws_size;

    const int NB  = (N + 255) / 256;
    const int NB1 = (N + 1 + 255) / 256;
    const int CB  = (E + 255) / 256;                                   // count blocks
    const int TB  = (IN_DIM * 256 + 2 * 256 * 256 + 255) / 256;        // transpose blocks
    const int XB  = (N * IN_DIM / 4 + 255) / 256;                      // convx blocks

    hipMemsetAsync(ws + zbeg, 0, zend - zbeg, stream);
    fused_misc_kernel<<<CB + TB + XB, 256, 0, stream>>>(
        dst, deg_cnt, E, W_in, WtIn, IN_DIM, W1, Wt1, W2, Wt2,
        x, xb, N * IN_DIM / 4, CB, TB);
    block_sum_kernel<<<NB, 256, 0, stream>>>(deg_cnt, bsums, N);
    bsum_scan_kernel<<<1, 256, 0, stream>>>(bsums, NB);
    scatter_scan_kernel<<<NB1, 256, 0, stream>>>(deg_cnt, bsums, offsets, cursor, dinv, N);
    fill_kernel<<<(E + 255) / 256, 256, 0, stream>>>(src, dst, cursor, csr, E);

    dim3 gg((N + 127) / 128, 2);
    gemm_bf16<0><<<gg, 256, 0, stream>>>(xb, WtIn, b_in, bufA, N, IN_DIM);
    gemm_bf16<1><<<gg, 256, 0, stream>>>(bufA, Wt1, dinv, bufB, N, 256);
    agg_kernel<<<(N + 3) / 4, 256, 0, stream>>>(bufB, offsets, csr, dinv, b1, bufA, N);
    gemm_bf16<1><<<gg, 256, 0, stream>>>(bufA, Wt2, dinv, bufB, N, 256);
    agg_kernel<<<(N + 3) / 4, 256, 0, stream>>>(bufB, offsets, csr, dinv, b2, bufA, N);

    const int PBLOCKS = 400;
    int chunk = (N + PBLOCKS - 1) / PBLOCKS;
    pool_partial_kernel<<<PBLOCKS, 256, 0, stream>>>(bufA, batch, sums, counts, N, chunk);
    pool_final_kernel<<<G, 256, 0, stream>>>(sums, counts, Wout, bout, (float*)d_out);
}

// Round 6
// 410.518 us; speedup vs baseline: 2.0918x; 1.0104x over previous
//
#include <hip/hip_runtime.h>
#include <hip/hip_bf16.h>

typedef __attribute__((ext_vector_type(8))) short bf16x8;   // 8 bf16 in 4 VGPRs (MFMA A/B frag)
typedef __attribute__((ext_vector_type(4))) float f32x4;    // MFMA C/D frag

__device__ __forceinline__ unsigned short f2bf(float f) {   // RNE fp32->bf16
    unsigned u = __float_as_uint(f);
    u += 0x7fff + ((u >> 16) & 1);
    return (unsigned short)(u >> 16);
}
__device__ __forceinline__ float bf2f(unsigned short s) {
    return __uint_as_float(((unsigned)s) << 16);
}

#define GL2LDS16(g, l) __builtin_amdgcn_global_load_lds(                      \
        (const __attribute__((address_space(1))) void*)(g),                   \
        (__attribute__((address_space(3))) void*)(l), 16, 0, 0)

// ---------------- fused setup: degree count + weight transposes + x->bf16 ----------------

__global__ __launch_bounds__(256) void fused_misc_kernel(
        const int* __restrict__ dst, int* __restrict__ cnt, int e,
        const float* __restrict__ Wa, unsigned short* __restrict__ Ta, int Ka,
        const float* __restrict__ Wb, unsigned short* __restrict__ Tb,
        const float* __restrict__ Wc, unsigned short* __restrict__ Tc,
        const float* __restrict__ x, unsigned short* __restrict__ xb, int n4,
        int CB, int TB) {
    int b = blockIdx.x;
    if (b < CB) {
        int i = b * 256 + threadIdx.x;
        if (i < e) atomicAdd(&cnt[dst[i]], 1);
    } else if (b < CB + TB) {
        int i = (b - CB) * 256 + threadIdx.x;
        int na = Ka * 256, nb = 256 * 256;
        if (i < na) {
            int k = i >> 8, n = i & 255;
            Ta[(size_t)n * Ka + k] = f2bf(Wa[i]);
        } else if (i < na + nb) {
            int j = i - na; int k = j >> 8, n = j & 255;
            Tb[(size_t)n * 256 + k] = f2bf(Wb[j]);
        } else if (i < na + 2 * nb) {
            int j = i - na - nb; int k = j >> 8, n = j & 255;
            Tc[(size_t)n * 256 + k] = f2bf(Wc[j]);
        }
    } else {
        int i = (b - CB - TB) * 256 + threadIdx.x;
        if (i < n4) {
            float4 v = ((const float4*)x)[i];
            ushort4 o;
            o.x = f2bf(v.x); o.y = f2bf(v.y); o.z = f2bf(v.z); o.w = f2bf(v.w);
            ((ushort4*)xb)[i] = o;
        }
    }
}

// ---------------- CSR scan (3-stage) ----------------

__global__ __launch_bounds__(256) void block_sum_kernel(const int* __restrict__ cnt,
                                                        int* __restrict__ bsums, int n) {
    int tid = threadIdx.x;
    int i = blockIdx.x * 256 + tid;
    int v = (i < n) ? cnt[i] : 0;
    #pragma unroll
    for (int off = 32; off > 0; off >>= 1) v += __shfl_down(v, off);
    __shared__ int ws[4];
    if ((tid & 63) == 0) ws[tid >> 6] = v;
    __syncthreads();
    if (tid == 0) bsums[blockIdx.x] = ws[0] + ws[1] + ws[2] + ws[3];
}

__global__ __launch_bounds__(256) void bsum_scan_kernel(int* __restrict__ bsums, int nb) {
    int tid = threadIdx.x;
    int lane = tid & 63, wid = tid >> 6;
    int v = (tid < nb) ? bsums[tid] : 0;
    int s = v;
    #pragma unroll
    for (int off = 1; off < 64; off <<= 1) {
        int t = __shfl_up(s, off);
        if (lane >= off) s += t;
    }
    __shared__ int ws[4];
    if (lane == 63) ws[wid] = s;
    __syncthreads();
    int wo = 0;
    #pragma unroll
    for (int k = 0; k < 4; ++k) wo += (k < wid) ? ws[k] : 0;
    if (tid < nb) bsums[tid] = wo + s - v;   // exclusive
}

__global__ __launch_bounds__(256) void scatter_scan_kernel(const int* __restrict__ cnt,
                                                           const int* __restrict__ bsums,
                                                           int* __restrict__ offsets,
                                                           int* __restrict__ cursor,
                                                           float* __restrict__ dinv, int n) {
    int tid = threadIdx.x;
    int lane = tid & 63, wid = tid >> 6;
    int i = blockIdx.x * 256 + tid;
    int v = (i < n) ? cnt[i] : 0;
    int s = v;
    #pragma unroll
    for (int off = 1; off < 64; off <<= 1) {
        int t = __shfl_up(s, off);
        if (lane >= off) s += t;
    }
    __shared__ int ws[4];
    if (lane == 63) ws[wid] = s;
    __syncthreads();
    int wo = 0;
    #pragma unroll
    for (int k = 0; k < 4; ++k) wo += (k < wid) ? ws[k] : 0;
    int excl = bsums[blockIdx.x] + wo + s - v;
    if (i <= n) { offsets[i] = excl; }
    if (i < n) {
        cursor[i] = excl;
        dinv[i] = rsqrtf((float)v + 1.0f);
    }
}

__global__ void fill_kernel(const int* __restrict__ src, const int* __restrict__ dst,
                            int* __restrict__ cursor, int* __restrict__ csr, int e) {
    int i = blockIdx.x * blockDim.x + threadIdx.x;
    if (i < e) {
        int p = atomicAdd(&cursor[dst[i]], 1);
        csr[p] = src[i];
    }
}

// ---------------- bf16 MFMA GEMM: C[M,256] = A[M,K] @ W[K,256] ----------------
// MODE 0: +bias[col]   MODE 1: *dinv[row]
// 128x128 tile, BK=64 (4 iters at K=256 -> half the barrier drains of BK=32).

template <int MODE>
__global__ __launch_bounds__(256) void gemm_bf16(const unsigned short* __restrict__ A,
                                                 const unsigned short* __restrict__ Wt,
                                                 const float* __restrict__ aux,
                                                 unsigned short* __restrict__ C,
                                                 int M, int K) {
    __shared__ unsigned short As[128 * 64];   // [row][k] 16 KB
    __shared__ unsigned short Bs[128 * 64];   // [col][k] 16 KB
    const int tid  = threadIdx.x;
    const int lane = tid & 63;
    const int w    = tid >> 6;
    const int wr   = w >> 1, wc = w & 1;
    const int row0 = blockIdx.x * 128;
    const int col0 = blockIdx.y * 128;
    const int mlane = lane & 15, quad = lane >> 4;

    f32x4 acc[4][4];
    #pragma unroll
    for (int i = 0; i < 4; ++i)
        #pragma unroll
        for (int j = 0; j < 4; ++j) acc[i][j] = f32x4{0.f, 0.f, 0.f, 0.f};

    // staging: 1024 chunks of 16 B per matrix per iter; round p, wave w owns
    // chunks [(p*4+w)*64, +64). chunk -> row = cid>>3, 16B-slot = cid&7.
    const unsigned short* gA[4]; const unsigned short* gB[4];
    unsigned short* lA[4]; unsigned short* lB[4];
    #pragma unroll
    for (int p = 0; p < 4; ++p) {
        int cid = (p * 4 + w) * 64 + lane;
        int row = cid >> 3, slot = cid & 7;
        int rowA = row0 + row; if (rowA >= M) rowA = M - 1;   // clamp (dup read, masked store)
        gA[p] = A + (size_t)rowA * K + slot * 8;
        gB[p] = Wt + (size_t)(col0 + row) * K + slot * 8;
        lA[p] = &As[((p * 4 + w) * 64) * 8];   // wave-uniform base; HW adds lane*16B
        lB[p] = &Bs[((p * 4 + w) * 64) * 8];
    }

    for (int k0 = 0; k0 < K; k0 += 64) {
        #pragma unroll
        for (int p = 0; p < 4; ++p) GL2LDS16(gA[p] + k0, lA[p]);
        #pragma unroll
        for (int p = 0; p < 4; ++p) GL2LDS16(gB[p] + k0, lB[p]);
        __syncthreads();
        #pragma unroll
        for (int ks = 0; ks < 2; ++ks) {
            bf16x8 af[4], bfv[4];
            #pragma unroll
            for (int i = 0; i < 4; ++i)
                af[i] = *(const bf16x8*)&As[(wr * 64 + i * 16 + mlane) * 64 + ks * 32 + quad * 8];
            #pragma unroll
            for (int j = 0; j < 4; ++j)
                bfv[j] = *(const bf16x8*)&Bs[(wc * 64 + j * 16 + mlane) * 64 + ks * 32 + quad * 8];
            #pragma unroll
            for (int i = 0; i < 4; ++i)
                #pragma unroll
                for (int j = 0; j < 4; ++j)
                    acc[i][j] = __builtin_amdgcn_mfma_f32_16x16x32_bf16(af[i], bfv[j], acc[i][j], 0, 0, 0);
        }
        __syncthreads();
    }

    float bj[4];
    if (MODE == 0) {
        #pragma unroll
        for (int j = 0; j < 4; ++j) bj[j] = aux[col0 + wc * 64 + j * 16 + mlane];
    }
    #pragma unroll
    for (int i = 0; i < 4; ++i) {
        #pragma unroll
        for (int r = 0; r < 4; ++r) {
            int grow = row0 + wr * 64 + i * 16 + quad * 4 + r;
            if (grow < M) {
                float d = (MODE == 1) ? aux[grow] : 0.f;
                #pragma unroll
                for (int j = 0; j < 4; ++j) {
                    int gcol = col0 + wc * 64 + j * 16 + mlane;
                    float v = acc[i][j][r];
                    v = (MODE == 0) ? (v + bj[j]) : (v * d);
                    C[(size_t)grow * 256 + gcol] = f2bf(v);
                }
            }
        }
    }
}

// ---------------- aggregation: index broadcast + 8-deep gather MLP ----------------

__global__ __launch_bounds__(256) void agg_kernel(const unsigned short* __restrict__ hs,
                                                  const int* __restrict__ offsets,
                                                  const int* __restrict__ csr,
                                                  const float* __restrict__ dinv,
                                                  const float* __restrict__ bias,
                                                  unsigned short* __restrict__ out, int n) {
    int node = blockIdx.x * 4 + (threadIdx.x >> 6);
    if (node >= n) return;
    int lane = threadIdx.x & 63;
    const ushort4* hs4 = (const ushort4*)hs;
    int beg = offsets[node], end = offsets[node + 1];
    ushort4 sv = hs4[(size_t)node * 64 + lane];
    float a0 = bf2f(sv.x), a1 = bf2f(sv.y), a2 = bf2f(sv.z), a3 = bf2f(sv.w);
    float c0 = 0.f, c1 = 0.f, c2 = 0.f, c3 = 0.f;

    int e = beg;
    while (e < end) {
        int cnt = end - e; if (cnt > 64) cnt = 64;
        int myi = (lane < cnt) ? csr[e + lane] : 0;
        int j = 0;
        for (; j + 8 <= cnt; j += 8) {
            int s0 = __shfl(myi, j + 0), s1 = __shfl(myi, j + 1);
            int s2 = __shfl(myi, j + 2), s3 = __shfl(myi, j + 3);
            int s4 = __shfl(myi, j + 4), s5 = __shfl(myi, j + 5);
            int s6 = __shfl(myi, j + 6), s7 = __shfl(myi, j + 7);
            ushort4 v0 = hs4[(size_t)s0 * 64 + lane];
            ushort4 v1 = hs4[(size_t)s1 * 64 + lane];
            ushort4 v2 = hs4[(size_t)s2 * 64 + lane];
            ushort4 v3 = hs4[(size_t)s3 * 64 + lane];
            ushort4 v4 = hs4[(size_t)s4 * 64 + lane];
            ushort4 v5 = hs4[(size_t)s5 * 64 + lane];
            ushort4 v6 = hs4[(size_t)s6 * 64 + lane];
            ushort4 v7 = hs4[(size_t)s7 * 64 + lane];
            a0 += bf2f(v0.x) + bf2f(v1.x) + bf2f(v2.x) + bf2f(v3.x);
            a1 += bf2f(v0.y) + bf2f(v1.y) + bf2f(v2.y) + bf2f(v3.y);
            a2 += bf2f(v0.z) + bf2f(v1.z) + bf2f(v2.z) + bf2f(v3.z);
            a3 += bf2f(v0.w) + bf2f(v1.w) + bf2f(v2.w) + bf2f(v3.w);
            c0 += bf2f(v4.x) + bf2f(v5.x) + bf2f(v6.x) + bf2f(v7.x);
            c1 += bf2f(v4.y) + bf2f(v5.y) + bf2f(v6.y) + bf2f(v7.y);
            c2 += bf2f(v4.z) + bf2f(v5.z) + bf2f(v6.z) + bf2f(v7.z);
            c3 += bf2f(v4.w) + bf2f(v5.w) + bf2f(v6.w) + bf2f(v7.w);
        }
        for (; j < cnt; ++j) {
            int s = __shfl(myi, j);
            ushort4 v = hs4[(size_t)s * 64 + lane];
            a0 += bf2f(v.x); a1 += bf2f(v.y); a2 += bf2f(v.z); a3 += bf2f(v.w);
        }
        e += cnt;
    }
    a0 += c0; a1 += c1; a2 += c2; a3 += c3;

    float d = dinv[node];
    float4 b = ((const float4*)bias)[lane];
    ushort4 r;
    r.x = f2bf(fmaxf(fmaf(a0, d, b.x), 0.f));
    r.y = f2bf(fmaxf(fmaf(a1, d, b.y), 0.f));
    r.z = f2bf(fmaxf(fmaf(a2, d, b.z), 0.f));
    r.w = f2bf(fmaxf(fmaf(a3, d, b.w), 0.f));
    ((ushort4*)out)[(size_t)node * 64 + lane] = r;
}

// ---------------- pooling ----------------

__global__ __launch_bounds__(256) void pool_partial_kernel(const unsigned short* __restrict__ h,
                                                           const int* __restrict__ batch,
                                                           float* __restrict__ sums,
                                                           int* __restrict__ counts,
                                                           int n, int chunk) {
    int beg = blockIdx.x * chunk;
    int end = beg + chunk; if (end > n) end = n;
    if (beg >= end) return;
    int c = threadIdx.x;
    int curg = batch[beg];
    float acc = 0.f;
    int runlen = 0;
    for (int i = beg; i < end; ++i) {
        int g = batch[i];
        if (g != curg) {
            atomicAdd(&sums[(size_t)curg * 256 + c], acc);
            if (c == 0) atomicAdd(&counts[curg], runlen);
            acc = 0.f; runlen = 0; curg = g;
        }
        acc += bf2f(h[(size_t)i * 256 + c]);
        ++runlen;
    }
    atomicAdd(&sums[(size_t)curg * 256 + c], acc);
    if (c == 0) atomicAdd(&counts[curg], runlen);
}

__global__ __launch_bounds__(256) void pool_final_kernel(const float* __restrict__ sums,
                                                         const int* __restrict__ counts,
                                                         const float* __restrict__ Wout,
                                                         const float* __restrict__ bout,
                                                         float* __restrict__ out) {
    __shared__ float pl[256];
    int g = blockIdx.x;
    int c = threadIdx.x;
    int cnt = counts[g];
    pl[c] = sums[(size_t)g * 256 + c] / (float)(cnt > 0 ? cnt : 1);
    __syncthreads();
    if (c < 16) {
        float o = bout[c];
        #pragma unroll 4
        for (int k = 0; k < 256; ++k) o = fmaf(pl[k], Wout[k * 16 + c], o);
        out[g * 16 + c] = o;
    }
}

// ---------------- launch ----------------

extern "C" void kernel_launch(void* const* d_in, const int* in_sizes, int n_in,
                              void* d_out, int out_size, void* d_ws, size_t ws_size,
                              hipStream_t stream) {
    const float* x     = (const float*)d_in[0];
    const int*   ei    = (const int*)d_in[1];
    const int*   batch = (const int*)d_in[2];
    const float* W_in  = (const float*)d_in[3];
    const float* b_in  = (const float*)d_in[4];
    const float* W1    = (const float*)d_in[5];
    const float* b1    = (const float*)d_in[6];
    const float* W2    = (const float*)d_in[7];
    const float* b2    = (const float*)d_in[8];
    const float* Wout  = (const float*)d_in[9];
    const float* bout  = (const float*)d_in[10];

    const int E = in_sizes[1] / 2;
    const int N = in_sizes[2];
    const int IN_DIM = in_sizes[0] / N;   // 128
    const int G = 128;
    const int* src = ei;
    const int* dst = ei + E;

    char* ws = (char*)d_ws;
    size_t off = 0;
    auto alloc = [&](size_t bytes) { size_t p = off; off += (bytes + 255) & ~(size_t)255; return p; };
    unsigned short* bufA = (unsigned short*)(ws + alloc((size_t)N * 256 * 2));
    unsigned short* bufB = (unsigned short*)(ws + alloc((size_t)N * 256 * 2));
    unsigned short* xb   = (unsigned short*)(ws + alloc((size_t)N * IN_DIM * 2));
    unsigned short* WtIn = (unsigned short*)(ws + alloc((size_t)IN_DIM * 256 * 2));
    unsigned short* Wt1  = (unsigned short*)(ws + alloc((size_t)256 * 256 * 2));
    unsigned short* Wt2  = (unsigned short*)(ws + alloc((size_t)256 * 256 * 2));
    size_t zbeg = off;
    int*   deg_cnt = (int*)(ws + alloc((size_t)N * 4));
    float* sums    = (float*)(ws + alloc((size_t)G * 256 * 4));
    int*   counts  = (int*)(ws + alloc((size_t)G * 4));
    size_t zend = off;
    float* dinv    = (float*)(ws + alloc((size_t)N * 4));
    int*   offsets = (int*)(ws + alloc((size_t)(N + 1) * 4));
    int*   cursor  = (int*)(ws + alloc((size_t)N * 4));
    int*   csr     = (int*)(ws + alloc((size_t)E * 4));
    int*   bsums   = (int*)(ws + alloc((size_t)256 * 4));
    (void)ws_size;

    const int NB  = (N + 255) / 256;
    const int NB1 = (N + 1 + 255) / 256;
    const int CB  = (E + 255) / 256;
    const int TB  = (IN_DIM * 256 + 2 * 256 * 256 + 255) / 256;
    const int XB  = (N * IN_DIM / 4 + 255) / 256;

    hipMemsetAsync(ws + zbeg, 0, zend - zbeg, stream);
    fused_misc_kernel<<<CB + TB + XB, 256, 0, stream>>>(
        dst, deg_cnt, E, W_in, WtIn, IN_DIM, W1, Wt1, W2, Wt2,
        x, xb, N * IN_DIM / 4, CB, TB);
    block_sum_kernel<<<NB, 256, 0, stream>>>(deg_cnt, bsums, N);
    bsum_scan_kernel<<<1, 256, 0, stream>>>(bsums, NB);
    scatter_scan_kernel<<<NB1, 256, 0, stream>>>(deg_cnt, bsums, offsets, cursor, dinv, N);
    fill_kernel<<<(E + 255) / 256, 256, 0, stream>>>(src, dst, cursor, csr, E);

    dim3 gg((N + 127) / 128, 2);
    gemm_bf16<0><<<gg, 256, 0, stream>>>(xb, WtIn, b_in, bufA, N, IN_DIM);
    gemm_bf16<1><<<gg, 256, 0, stream>>>(bufA, Wt1, dinv, bufB, N, 256);
    agg_kernel<<<(N + 3) / 4, 256, 0, stream>>>(bufB, offsets, csr, dinv, b1, bufA, N);
    gemm_bf16<1><<<gg, 256, 0, stream>>>(bufA, Wt2, dinv, bufB, N, 256);
    agg_kernel<<<(N + 3) / 4, 256, 0, stream>>>(bufB, offsets, csr, dinv, b2, bufA, N);

    const int PBLOCKS = 400;
    int chunk = (N + PBLOCKS - 1) / PBLOCKS;
    pool_partial_kernel<<<PBLOCKS, 256, 0, stream>>>(bufA, batch, sums, counts, N, chunk);
    pool_final_kernel<<<G, 256, 0, stream>>>(sums, counts, Wout, bout, (float*)d_out);
}